// Round 14
// baseline (190.307 us; speedup 1.0000x reference)
//
#include <hip/hip_runtime.h>
#include <hip/hip_bf16.h>
#include <math.h>

typedef __bf16 bf16;
typedef __bf16 bf16x8 __attribute__((ext_vector_type(8)));
typedef __bf16 bf16x4 __attribute__((ext_vector_type(4)));
typedef float f32x4 __attribute__((ext_vector_type(4)));
typedef float f32x16 __attribute__((ext_vector_type(16)));

#define MFMA16(a, b, c) __builtin_amdgcn_mfma_f32_16x16x32_bf16(a, b, c, 0, 0, 0)
#define MFMA32(a, b, c) __builtin_amdgcn_mfma_f32_32x32x16_bf16(a, b, c, 0, 0, 0)

// softmax scale (C^-0.5) * log2(e), folded into K values at qkv epilogue
#define SCALEK 0.09016844005555896f

typedef const __attribute__((address_space(1))) void* gas_t;
typedef __attribute__((address_space(3))) void* las_t;

// ---------------------------------------------------------------------------
// Kernel 0: convert qkv_w fp32 -> bf16 (once). 768*256 = 196608 elems.
// ---------------------------------------------------------------------------
__global__ __launch_bounds__(256) void wcvt_kernel(const float* __restrict__ qw,
                                                   bf16* __restrict__ qwb) {
  int t = blockIdx.x * 256 + threadIdx.x;  // 49152 threads x 4 elems
  float4 v = *(const float4*)(qw + (size_t)t * 4);
  bf16x4 o;
  o[0] = (bf16)v.x; o[1] = (bf16)v.y; o[2] = (bf16)v.z; o[3] = (bf16)v.w;
  *(bf16x4*)(qwb + (size_t)t * 4) = o;
}

// ---------------------------------------------------------------------------
// Kernel 1: GroupNorm  x(fp32, b,c,hw) -> h(bf16, b,c,hw)
// ---------------------------------------------------------------------------
__global__ __launch_bounds__(256) void gn_kernel(
    const float* __restrict__ x, const float* __restrict__ gw,
    const float* __restrict__ gb, bf16* __restrict__ h) {
  const int bg = blockIdx.x;            // 0..127
  const int b = bg >> 5, g = bg & 31;
  const size_t base = (size_t)(b * 256 + g * 8) * 4096;
  const float* xp = x + base;
  bf16* hp = h + base;
  const int tid = threadIdx.x;

  float s = 0.f, ss = 0.f;
  for (int i = tid * 4; i < 32768; i += 1024) {
    float4 v = *(const float4*)(xp + i);
    s += v.x + v.y + v.z + v.w;
    ss += v.x * v.x + v.y * v.y + v.z * v.z + v.w * v.w;
  }
#pragma unroll
  for (int off = 32; off; off >>= 1) {
    s += __shfl_down(s, off);
    ss += __shfl_down(ss, off);
  }
  __shared__ float red[8];
  if ((tid & 63) == 0) {
    red[(tid >> 6) * 2] = s;
    red[(tid >> 6) * 2 + 1] = ss;
  }
  __syncthreads();
  s = red[0] + red[2] + red[4] + red[6];
  ss = red[1] + red[3] + red[5] + red[7];
  const float mean = s * (1.f / 32768.f);
  const float var = ss * (1.f / 32768.f) - mean * mean;
  const float rstd = rsqrtf(var + 1e-5f);

  for (int i = tid * 4; i < 32768; i += 1024) {
    float4 v = *(const float4*)(xp + i);
    int c = g * 8 + (i >> 12);
    float a = gw[c] * rstd;
    float b2 = gb[c] - mean * a;
    bf16x4 o;
    o[0] = (bf16)(v.x * a + b2);
    o[1] = (bf16)(v.y * a + b2);
    o[2] = (bf16)(v.z * a + b2);
    o[3] = (bf16)(v.w * a + b2);
    *(bf16x4*)(hp + i) = o;
  }
}

// ---------------------------------------------------------------------------
// Kernel 2: QKV GEMM (A = pre-converted bf16 w via global_load_lds, dbuf,
// 1 barrier/K-step). K output pre-scaled by SCALEK.
// ---------------------------------------------------------------------------
__global__ __launch_bounds__(256) void qkv_gemm(
    const bf16* __restrict__ h, const bf16* __restrict__ wb,
    const float* __restrict__ bias, bf16* __restrict__ qt,
    bf16* __restrict__ kt, bf16* __restrict__ vcm) {
  const int b = blockIdx.z;
  const int o0 = blockIdx.y * 64;
  const int p0 = blockIdx.x * 64;
  __shared__ bf16 Alds[2][64][32];
  __shared__ bf16 Blds[2][64][56];
  const int tid = threadIdx.x;
  const int lane = tid & 63, wid = tid >> 6;
  const int lr = lane & 15, lg = lane >> 4;
  const int wm = wid >> 1, wn = wid & 1;
  const bf16* hb = h + (size_t)b * 256 * 4096;

  const int arow = tid >> 2, ac8 = (tid & 3) * 8;
  const int bcc = tid >> 3, bp8 = (tid & 7) * 8;

#define QKV_STAGE_A(K0, BUF)                                                  \
  __builtin_amdgcn_global_load_lds(                                           \
      (gas_t)(const void*)(wb + (size_t)(o0 + arow) * 256 + (K0) + ac8),      \
      (las_t)(void*)(&Alds[BUF][0][0] + tid * 8), 16, 0, 0);

  f32x4 acc[2][2] = {};

  QKV_STAGE_A(0, 0);
  {
    bf16x8 v = *(const bf16x8*)(hb + (size_t)bcc * 4096 + p0 + bp8);
#pragma unroll
    for (int e = 0; e < 8; ++e) Blds[0][bp8 + e][bcc] = v[e];
  }
  __syncthreads();

  for (int k = 0; k < 8; ++k) {
    const int cur = k & 1, nb = cur ^ 1;
    if (k < 7) {
      QKV_STAGE_A((k + 1) * 32, nb);
      bf16x8 v =
          *(const bf16x8*)(hb + (size_t)((k + 1) * 32 + bcc) * 4096 + p0 + bp8);
#pragma unroll
      for (int e = 0; e < 8; ++e) Blds[nb][bp8 + e][bcc] = v[e];
    }
    bf16x8 af[2], bfr[2];
#pragma unroll
    for (int mi = 0; mi < 2; ++mi)
      af[mi] = *(const bf16x8*)&Alds[cur][wm * 32 + mi * 16 + lr][lg * 8];
#pragma unroll
    for (int ni = 0; ni < 2; ++ni)
      bfr[ni] = *(const bf16x8*)&Blds[cur][wn * 32 + ni * 16 + lr][lg * 8];
#pragma unroll
    for (int mi = 0; mi < 2; ++mi)
#pragma unroll
      for (int ni = 0; ni < 2; ++ni)
        acc[mi][ni] = MFMA16(af[mi], bfr[ni], acc[mi][ni]);
    __syncthreads();
  }
#undef QKV_STAGE_A

#pragma unroll
  for (int mi = 0; mi < 2; ++mi) {
#pragma unroll
    for (int ni = 0; ni < 2; ++ni) {
#pragma unroll
      for (int r = 0; r < 4; ++r) {
        int o = o0 + wm * 32 + mi * 16 + lg * 4 + r;
        int p = p0 + wn * 32 + ni * 16 + lr;
        float val = acc[mi][ni][r] + bias[o];
        if (o < 256) {
          qt[((size_t)b * 4096 + p) * 256 + o] = (bf16)val;
        } else if (o < 512) {
          kt[((size_t)b * 4096 + p) * 256 + (o - 256)] = (bf16)(val * SCALEK);
        } else {
          vcm[((size_t)b * 256 + (o - 512)) * 4096 + p] = (bf16)val;
        }
      }
    }
  }
}

// ---------------------------------------------------------------------------
// Kernel 3: flash attention, swapped-operand 32x32x16, SW-pipelined fused
// cluster [QK(t+1) || PV(t)]. QBLK=256 (8 waves), ring-2 (64 KB LDS),
// 2 blocks/CU. S splits sized so grid = 2 x 256 CUs (S=8 -> 512 blocks:
// the r13 grid of 256 blocks left HALF the GPU idle).
// m==0 softmax (log2 domain), lane-local q=lane&31. XCD-pinned combos.
// ---------------------------------------------------------------------------
template <int S>
__global__ __launch_bounds__(512, 2) void flash_attn(
    const bf16* __restrict__ qt, const bf16* __restrict__ kt,
    const bf16* __restrict__ vcm, bf16* __restrict__ Opart,
    float* __restrict__ l_g) {
  constexpr int NCOMBO = 4 * S;
  constexpr int CSH = (S == 8) ? 5 : (S == 4) ? 4 : (S == 2) ? 3 : 2;
  constexpr int NIT = (4096 / S) / 32;
  const int bid = blockIdx.x;
  const int combo = bid & (NCOMBO - 1);
  const int qtile = bid >> CSH;
  const int b = combo & 3;
  const int split = combo >> 2;
  const int i0 = qtile * 256;
  const int jbase = split * (4096 / S);

  __shared__ bf16 Klds[2][32][256];  // granule16 ^= (row&7) at stage
  __shared__ bf16 Vlds[2][256][32];  // granule16 ^= ((row>>2)&3) at stage
  const int tid = threadIdx.x;
  const int lane = tid & 63, w = tid >> 6;
  const int ln = lane & 31;   // q index (B col) / LDS row
  const int hv = lane >> 5;   // lane half
  const bf16* qb = qt + (size_t)b * 4096 * 256;
  const bf16* kb = kt + (size_t)b * 4096 * 256;
  const bf16* vb = vcm + (size_t)b * 256 * 4096;

  // Q^T B-fragments (registers, loaded once); wave w owns q rows i0+w*32..+31
  const int qrow = i0 + w * 32 + ln;
  bf16x8 qf[16];
#pragma unroll
  for (int ks = 0; ks < 16; ++ks)
    qf[ks] = *(const bf16x8*)(qb + (size_t)qrow * 256 + ks * 16 + hv * 8);

  // staging lane offsets: 1024 16B-chunks per K tile / per V tile, 512 thr
  int koff[2], voff[2];
#pragma unroll
  for (int it = 0; it < 2; ++it) {
    int chunk = tid + 512 * it;
    int krow = chunk >> 5;
    koff[it] = krow * 256 + ((((chunk & 31) ^ (krow & 7)) * 8));
    int vrow = chunk >> 2;
    voff[it] = vrow * 4096 + (((chunk & 3) ^ ((vrow >> 2) & 3)) * 8);
  }

#define STAGE_K(JT, BUF)                                                      \
  {                                                                           \
    const int j0s = jbase + (JT) * 32;                                        \
    _Pragma("unroll") for (int it = 0; it < 2; ++it) {                        \
      int chunk = tid + 512 * it;                                             \
      __builtin_amdgcn_global_load_lds(                                       \
          (gas_t)(const void*)(kb + (size_t)j0s * 256 + koff[it]),            \
          (las_t)(void*)(&Klds[BUF][0][0] + chunk * 8), 16, 0, 0);            \
    }                                                                         \
  }
#define STAGE_V(JT, BUF)                                                      \
  {                                                                           \
    const int j0s = jbase + (JT) * 32;                                        \
    _Pragma("unroll") for (int it = 0; it < 2; ++it) {                        \
      int chunk = tid + 512 * it;                                             \
      __builtin_amdgcn_global_load_lds(                                       \
          (gas_t)(const void*)(vb + (size_t)j0s + voff[it]),                  \
          (las_t)(void*)(&Vlds[BUF][0][0] + chunk * 8), 16, 0, 0);            \
    }                                                                         \
  }

  float llane = 0.f;
  f32x16 accO[8] = {};
  const int kswz = ln & 7;
  const int vswz = (ln >> 2) & 3;

  // prologue: tile 0 fully staged, then QK(0), then issue K(1)
  STAGE_K(0, 0);
  STAGE_V(0, 0);
  asm volatile("s_waitcnt vmcnt(0)" ::: "memory");
  __builtin_amdgcn_s_barrier();

  f32x16 a0 = {}, a1 = {};
#pragma unroll
  for (int ks = 0; ks < 8; ++ks) {
    bf16x8 kf0 = *(const bf16x8*)&Klds[0][ln][((2 * ks + hv) ^ kswz) * 8];
    bf16x8 kf1 =
        *(const bf16x8*)&Klds[0][ln][((2 * (ks + 8) + hv) ^ kswz) * 8];
    a0 = MFMA32(kf0, qf[ks], a0);
    a1 = MFMA32(kf1, qf[ks + 8], a1);
  }
  if (NIT > 1) STAGE_K(1, 1);

  for (int t = 0; t < NIT; ++t) {
    // everything issued last iteration (V(t), K(t+1)) has landed
    asm volatile("s_waitcnt vmcnt(0)" ::: "memory");
    __builtin_amdgcn_s_barrier();

    // prefetch: V one tile ahead, K two tiles ahead (ring-2)
    if (t + 1 < NIT) STAGE_V(t + 1, (t + 1) & 1);
    if (t + 2 < NIT) STAGE_K(t + 2, t & 1);

    // softmax(t): lane-local, m == 0
    float pv[16];
#pragma unroll
    for (int r = 0; r < 16; ++r) pv[r] = exp2f(a0[r] + a1[r]);
    llane += (((pv[0] + pv[1]) + (pv[2] + pv[3])) +
              ((pv[4] + pv[5]) + (pv[6] + pv[7]))) +
             (((pv[8] + pv[9]) + (pv[10] + pv[11])) +
              ((pv[12] + pv[13]) + (pv[14] + pv[15])));

    int pk[8];
#pragma unroll
    for (int q4 = 0; q4 < 8; ++q4)
      asm("v_cvt_pk_bf16_f32 %0, %1, %2"
          : "=v"(pk[q4])
          : "v"(pv[q4 * 2]), "v"(pv[q4 * 2 + 1]));
    bf16x8 pfrag[2];
#pragma unroll
    for (int s = 0; s < 2; ++s) {
      int xa = pk[s * 4 + 0], ya = pk[s * 4 + 2];
      int xb = pk[s * 4 + 1], yb = pk[s * 4 + 3];
      asm("v_permlane32_swap_b32 %0, %1" : "+v"(xa), "+v"(ya));
      asm("v_permlane32_swap_b32 %0, %1" : "+v"(xb), "+v"(yb));
      union { int i[4]; bf16x8 v; } u;
      u.i[0] = xa; u.i[1] = xb; u.i[2] = ya; u.i[3] = yb;
      pfrag[s] = u.v;
    }

    // fused MFMA cluster: QK(t+1) || PV(t)  (independent chains)
    const bf16(*Kc)[256] = Klds[(t + 1) & 1];
    const bf16(*Vc)[32] = Vlds[t & 1];
    __builtin_amdgcn_s_setprio(1);
    if (t + 1 < NIT) {
      f32x16 n0 = {}, n1 = {};
#pragma unroll
      for (int u = 0; u < 8; ++u) {
        bf16x8 kf0 = *(const bf16x8*)&Kc[ln][((2 * u + hv) ^ kswz) * 8];
        n0 = MFMA32(kf0, qf[u], n0);
        bf16x8 kf1 =
            *(const bf16x8*)&Kc[ln][((2 * (u + 8) + hv) ^ kswz) * 8];
        n1 = MFMA32(kf1, qf[u + 8], n1);
        bf16x8 vf0 = *(const bf16x8*)&Vc[u * 32 + ln][((hv) ^ vswz) * 8];
        accO[u] = MFMA32(vf0, pfrag[0], accO[u]);
        bf16x8 vf1 = *(const bf16x8*)&Vc[u * 32 + ln][((2 + hv) ^ vswz) * 8];
        accO[u] = MFMA32(vf1, pfrag[1], accO[u]);
      }
      a0 = n0;
      a1 = n1;
    } else {
#pragma unroll
      for (int u = 0; u < 8; ++u) {
        bf16x8 vf0 = *(const bf16x8*)&Vc[u * 32 + ln][((hv) ^ vswz) * 8];
        accO[u] = MFMA32(vf0, pfrag[0], accO[u]);
        bf16x8 vf1 = *(const bf16x8*)&Vc[u * 32 + ln][((2 + hv) ^ vswz) * 8];
        accO[u] = MFMA32(vf1, pfrag[1], accO[u]);
      }
    }
    __builtin_amdgcn_s_setprio(0);
  }
#undef STAGE_K
#undef STAGE_V

  // epilogue: store unnormalized O rows (q = qrow), pack f32->bf16 pairs
  bf16* ob = Opart + ((size_t)(split * 4 + b) * 4096 + qrow) * 256;
#pragma unroll
  for (int cb = 0; cb < 8; ++cb) {
#pragma unroll
    for (int g = 0; g < 4; ++g) {
      int lo, hi;
      asm("v_cvt_pk_bf16_f32 %0, %1, %2"
          : "=v"(lo)
          : "v"(accO[cb][g * 4 + 0]), "v"(accO[cb][g * 4 + 1]));
      asm("v_cvt_pk_bf16_f32 %0, %1, %2"
          : "=v"(hi)
          : "v"(accO[cb][g * 4 + 2]), "v"(accO[cb][g * 4 + 3]));
      int2 val; val.x = lo; val.y = hi;
      *(int2*)(ob + cb * 32 + g * 8 + hv * 4) = val;
    }
  }
  // l: combine lane halves with one permlane32_swap
  {
    int xa = __float_as_int(llane);
    int ya = xa;
    asm("v_permlane32_swap_b32 %0, %1" : "+v"(xa), "+v"(ya));
    float ltot = __int_as_float(xa) + __int_as_float(ya);
    if (hv == 0)
      l_g[(size_t)(split * 4 + b) * 4096 + qrow] = ltot;
  }
}

// ---------------------------------------------------------------------------
// Kernel 4: proj GEMM + bias + residual, fused split-merge + normalize.
// ---------------------------------------------------------------------------
template <int S>
__global__ __launch_bounds__(256) void proj_fused(
    const bf16* __restrict__ Opart, const float* __restrict__ l_g,
    const float* __restrict__ w, const float* __restrict__ bias,
    const float* __restrict__ x, float* __restrict__ out) {
  const int b = blockIdx.y;
  const int p0 = blockIdx.x * 64;
  __shared__ bf16 Wlds[256][32];
  __shared__ bf16 Blds[64][32];
  __shared__ float Linv[64];
  const int tid = threadIdx.x;
  const int lane = tid & 63, wid = tid >> 6;
  const int lr = lane & 15, lg = lane >> 4;

  if (tid < 64) {
    float L = 0.f;
#pragma unroll
    for (int s = 0; s < S; ++s)
      L += l_g[(size_t)(s * 4 + b) * 4096 + p0 + tid];
    Linv[tid] = 1.f / L;
  }
  __syncthreads();

  const int pr = tid >> 2, c8b = (tid & 3) * 8;
  const float invp = Linv[pr];

  float4 wreg[4][2];
  bf16x8 breg[S];

#define PROJ_READ(K0)                                                         \
  {                                                                           \
    _Pragma("unroll") for (int it = 0; it < 4; ++it) {                        \
      int chunk = tid + 256 * it;                                             \
      int row = chunk >> 2, c8 = (chunk & 3) * 8;                             \
      const float* src = w + (size_t)row * 256 + (K0) + c8;                   \
      wreg[it][0] = *(const float4*)src;                                      \
      wreg[it][1] = *(const float4*)(src + 4);                                \
    }                                                                         \
    _Pragma("unroll") for (int s = 0; s < S; ++s) breg[s] =                   \
        *(const bf16x8*)(Opart +                                              \
                         ((size_t)(s * 4 + b) * 4096 + p0 + pr) * 256 +       \
                         (K0) + c8b);                                         \
  }
#define PROJ_WRITE()                                                          \
  {                                                                           \
    _Pragma("unroll") for (int it = 0; it < 4; ++it) {                        \
      int chunk = tid + 256 * it;                                             \
      int row = chunk >> 2, c8 = (chunk & 3) * 8;                             \
      bf16x8 bv;                                                              \
      bv[0] = (bf16)wreg[it][0].x; bv[1] = (bf16)wreg[it][0].y;               \
      bv[2] = (bf16)wreg[it][0].z; bv[3] = (bf16)wreg[it][0].w;               \
      bv[4] = (bf16)wreg[it][1].x; bv[5] = (bf16)wreg[it][1].y;               \
      bv[6] = (bf16)wreg[it][1].z; bv[7] = (bf16)wreg[it][1].w;               \
      *(bf16x8*)&Wlds[row][c8] = bv;                                          \
    }                                                                         \
    {                                                                         \
      float a8[8] = {};                                                       \
      _Pragma("unroll") for (int s = 0; s < S; ++s) {                         \
        _Pragma("unroll") for (int e = 0; e < 8; ++e) a8[e] +=                \
            (float)breg[s][e];                                                \
      }                                                                       \
      bf16x8 bv;                                                              \
      _Pragma("unroll") for (int e = 0; e < 8; ++e) bv[e] =                   \
          (bf16)(a8[e] * invp);                                               \
      *(bf16x8*)&Blds[pr][c8b] = bv;                                          \
    }                                                                         \
  }

  f32x4 acc[4][4] = {};

  PROJ_READ(0);
  PROJ_WRITE();
  __syncthreads();

  for (int k = 0; k < 8; ++k) {
    if (k < 7) PROJ_READ((k + 1) * 32);

    bf16x8 af[4], bfr[4];
#pragma unroll
    for (int mi = 0; mi < 4; ++mi)
      af[mi] = *(const bf16x8*)&Wlds[wid * 64 + mi * 16 + lr][lg * 8];
#pragma unroll
    for (int ni = 0; ni < 4; ++ni)
      bfr[ni] = *(const bf16x8*)&Blds[ni * 16 + lr][lg * 8];
#pragma unroll
    for (int mi = 0; mi < 4; ++mi)
#pragma unroll
      for (int ni = 0; ni < 4; ++ni)
        acc[mi][ni] = MFMA16(af[mi], bfr[ni], acc[mi][ni]);

    __syncthreads();
    if (k < 7) {
      PROJ_WRITE();
      __syncthreads();
    }
  }
#undef PROJ_READ
#undef PROJ_WRITE

#pragma unroll
  for (int mi = 0; mi < 4; ++mi) {
#pragma unroll
    for (int ni = 0; ni < 4; ++ni) {
#pragma unroll
      for (int r = 0; r < 4; ++r) {
        int o = wid * 64 + mi * 16 + lg * 4 + r;
        int p = p0 + ni * 16 + lr;
        size_t idx = ((size_t)b * 256 + o) * 4096 + p;
        out[idx] = acc[mi][ni][r] + bias[o] + x[idx];
      }
    }
  }
}

// ---------------------------------------------------------------------------
extern "C" void kernel_launch(void* const* d_in, const int* in_sizes, int n_in,
                              void* d_out, int out_size, void* d_ws,
                              size_t ws_size, hipStream_t stream) {
  (void)in_sizes; (void)n_in; (void)out_size;
  const float* x = (const float*)d_in[0];
  const float* gn_w = (const float*)d_in[1];
  const float* gn_b = (const float*)d_in[2];
  const float* qkv_w = (const float*)d_in[3];
  const float* qkv_b = (const float*)d_in[4];
  const float* proj_w = (const float*)d_in[5];
  const float* proj_b = (const float*)d_in[6];
  float* out = (float*)d_out;

  const size_t MB = 1024ull * 1024ull;
  char* ws = (char*)d_ws;
  bf16* h = (bf16*)(ws);
  bf16* qt = (bf16*)(ws + 8 * MB);
  bf16* kt = (bf16*)(ws + 16 * MB);
  bf16* vcm = (bf16*)(ws + 24 * MB);

  // pick split count by available scratch: Opart = S*8MB, l_g = S*4*4096*4B
  int S;
  if (ws_size >= 32 * MB + 8 * 8 * MB + 8ull * 4 * 4096 * sizeof(float)) S = 8;
  else if (ws_size >= 32 * MB + 4 * 8 * MB + 4ull * 16384 * sizeof(float)) S = 4;
  else if (ws_size >= 32 * MB + 2 * 8 * MB + 2ull * 16384 * sizeof(float)) S = 2;
  else S = 1;

  bf16* Opart;
  float* l_g;
  bf16* qwb;  // bf16 copy of qkv_w (384 KB), parked where flash writes later
  if (S >= 2) {
    Opart = (bf16*)(ws + 32 * MB);
    l_g = (float*)(ws + 32 * MB + (size_t)S * 8 * MB);
    qwb = Opart;  // overwritten by flash AFTER qkv has consumed it
  } else {
    Opart = h;
    l_g = (float*)(ws + 32 * MB);
    qwb = (bf16*)(ws + 32 * MB + 256 * 1024);
  }

  wcvt_kernel<<<192, 256, 0, stream>>>(qkv_w, qwb);
  gn_kernel<<<128, 256, 0, stream>>>(x, gn_w, gn_b, h);
  qkv_gemm<<<dim3(64, 12, 4), 256, 0, stream>>>(h, qwb, qkv_b, qt, kt, vcm);
  if (S == 8) {
    flash_attn<8><<<16 * 32, 512, 0, stream>>>(qt, kt, vcm, Opart, l_g);
    proj_fused<8><<<dim3(64, 4), 256, 0, stream>>>(Opart, l_g, proj_w, proj_b,
                                                   x, out);
  } else if (S == 4) {
    flash_attn<4><<<16 * 16, 512, 0, stream>>>(qt, kt, vcm, Opart, l_g);
    proj_fused<4><<<dim3(64, 4), 256, 0, stream>>>(Opart, l_g, proj_w, proj_b,
                                                   x, out);
  } else if (S == 2) {
    flash_attn<2><<<16 * 8, 512, 0, stream>>>(qt, kt, vcm, Opart, l_g);
    proj_fused<2><<<dim3(64, 4), 256, 0, stream>>>(Opart, l_g, proj_w, proj_b,
                                                   x, out);
  } else {
    flash_attn<1><<<16 * 4, 512, 0, stream>>>(qt, kt, vcm, Opart, l_g);
    proj_fused<1><<<dim3(64, 4), 256, 0, stream>>>(Opart, l_g, proj_w, proj_b,
                                                   x, out);
  }
}

// Round 15
// 158.840 us; speedup vs baseline: 1.1981x; 1.1981x over previous
//
#include <hip/hip_runtime.h>
#include <hip/hip_bf16.h>
#include <math.h>

typedef __bf16 bf16;
typedef __bf16 bf16x8 __attribute__((ext_vector_type(8)));
typedef __bf16 bf16x4 __attribute__((ext_vector_type(4)));
typedef float f32x4 __attribute__((ext_vector_type(4)));
typedef float f32x16 __attribute__((ext_vector_type(16)));

#define MFMA16(a, b, c) __builtin_amdgcn_mfma_f32_16x16x32_bf16(a, b, c, 0, 0, 0)
#define MFMA32(a, b, c) __builtin_amdgcn_mfma_f32_32x32x16_bf16(a, b, c, 0, 0, 0)

// softmax scale (C^-0.5) * log2(e), folded into K values at qkv epilogue
#define SCALEK 0.09016844005555896f

typedef const __attribute__((address_space(1))) void* gas_t;
typedef __attribute__((address_space(3))) void* las_t;

// ---------------------------------------------------------------------------
// Kernel 0: convert qkv_w fp32 -> bf16 (once). 768*256 = 196608 elems.
// ---------------------------------------------------------------------------
__global__ __launch_bounds__(256) void wcvt_kernel(const float* __restrict__ qw,
                                                   bf16* __restrict__ qwb) {
  int t = blockIdx.x * 256 + threadIdx.x;  // 49152 threads x 4 elems
  float4 v = *(const float4*)(qw + (size_t)t * 4);
  bf16x4 o;
  o[0] = (bf16)v.x; o[1] = (bf16)v.y; o[2] = (bf16)v.z; o[3] = (bf16)v.w;
  *(bf16x4*)(qwb + (size_t)t * 4) = o;
}

// ---------------------------------------------------------------------------
// Kernel 1a: GroupNorm stats. 1024 blocks = one 4096-elem channel plane each.
// Writes partial (sum, sumsq) per plane; full-device parallelism (no atomics).
// ---------------------------------------------------------------------------
__global__ __launch_bounds__(256) void gn_stats(const float* __restrict__ x,
                                                float* __restrict__ pstats) {
  const int bid = blockIdx.x;                 // plane = b*256 + c
  const float* xp = x + (size_t)bid * 4096;
  const int tid = threadIdx.x;

  float s = 0.f, ss = 0.f;
#pragma unroll
  for (int i = 0; i < 4; ++i) {
    float4 v = *(const float4*)(xp + tid * 4 + i * 1024);
    s += v.x + v.y + v.z + v.w;
    ss += v.x * v.x + v.y * v.y + v.z * v.z + v.w * v.w;
  }
#pragma unroll
  for (int off = 32; off; off >>= 1) {
    s += __shfl_down(s, off);
    ss += __shfl_down(ss, off);
  }
  __shared__ float red[8];
  if ((tid & 63) == 0) {
    red[(tid >> 6) * 2] = s;
    red[(tid >> 6) * 2 + 1] = ss;
  }
  __syncthreads();
  if (tid == 0) {
    pstats[bid * 2] = red[0] + red[2] + red[4] + red[6];
    pstats[bid * 2 + 1] = red[1] + red[3] + red[5] + red[7];
  }
}

// ---------------------------------------------------------------------------
// Kernel 1b: GroupNorm apply. 1024 blocks; each sums its group's 8 plane
// partials (uniform loads) and normalizes its plane -> h (bf16).
// ---------------------------------------------------------------------------
__global__ __launch_bounds__(256) void gn_apply(
    const float* __restrict__ x, const float* __restrict__ pstats,
    const float* __restrict__ gw, const float* __restrict__ gb,
    bf16* __restrict__ h) {
  const int bid = blockIdx.x;
  const int c = bid & 255;
  const int gbase = bid & ~7;                 // first plane of this group
  const float* xp = x + (size_t)bid * 4096;
  bf16* hp = h + (size_t)bid * 4096;
  const int tid = threadIdx.x;

  float s = 0.f, ss = 0.f;
#pragma unroll
  for (int i = 0; i < 8; ++i) {
    s += pstats[(gbase + i) * 2];
    ss += pstats[(gbase + i) * 2 + 1];
  }
  const float mean = s * (1.f / 32768.f);
  const float var = ss * (1.f / 32768.f) - mean * mean;
  const float rstd = rsqrtf(var + 1e-5f);
  const float a = gw[c] * rstd;
  const float b2 = gb[c] - mean * a;

#pragma unroll
  for (int i = 0; i < 4; ++i) {
    float4 v = *(const float4*)(xp + tid * 4 + i * 1024);
    bf16x4 o;
    o[0] = (bf16)(v.x * a + b2);
    o[1] = (bf16)(v.y * a + b2);
    o[2] = (bf16)(v.z * a + b2);
    o[3] = (bf16)(v.w * a + b2);
    *(bf16x4*)(hp + tid * 4 + i * 1024) = o;
  }
}

// ---------------------------------------------------------------------------
// Kernel 2: QKV GEMM (A = pre-converted bf16 w via global_load_lds, dbuf,
// 1 barrier/K-step). K output pre-scaled by SCALEK.
// ---------------------------------------------------------------------------
__global__ __launch_bounds__(256) void qkv_gemm(
    const bf16* __restrict__ h, const bf16* __restrict__ wb,
    const float* __restrict__ bias, bf16* __restrict__ qt,
    bf16* __restrict__ kt, bf16* __restrict__ vcm) {
  const int b = blockIdx.z;
  const int o0 = blockIdx.y * 64;
  const int p0 = blockIdx.x * 64;
  __shared__ bf16 Alds[2][64][32];
  __shared__ bf16 Blds[2][64][56];
  const int tid = threadIdx.x;
  const int lane = tid & 63, wid = tid >> 6;
  const int lr = lane & 15, lg = lane >> 4;
  const int wm = wid >> 1, wn = wid & 1;
  const bf16* hb = h + (size_t)b * 256 * 4096;

  const int arow = tid >> 2, ac8 = (tid & 3) * 8;
  const int bcc = tid >> 3, bp8 = (tid & 7) * 8;

#define QKV_STAGE_A(K0, BUF)                                                  \
  __builtin_amdgcn_global_load_lds(                                           \
      (gas_t)(const void*)(wb + (size_t)(o0 + arow) * 256 + (K0) + ac8),      \
      (las_t)(void*)(&Alds[BUF][0][0] + tid * 8), 16, 0, 0);

  f32x4 acc[2][2] = {};

  QKV_STAGE_A(0, 0);
  {
    bf16x8 v = *(const bf16x8*)(hb + (size_t)bcc * 4096 + p0 + bp8);
#pragma unroll
    for (int e = 0; e < 8; ++e) Blds[0][bp8 + e][bcc] = v[e];
  }
  __syncthreads();

  for (int k = 0; k < 8; ++k) {
    const int cur = k & 1, nb = cur ^ 1;
    if (k < 7) {
      QKV_STAGE_A((k + 1) * 32, nb);
      bf16x8 v =
          *(const bf16x8*)(hb + (size_t)((k + 1) * 32 + bcc) * 4096 + p0 + bp8);
#pragma unroll
      for (int e = 0; e < 8; ++e) Blds[nb][bp8 + e][bcc] = v[e];
    }
    bf16x8 af[2], bfr[2];
#pragma unroll
    for (int mi = 0; mi < 2; ++mi)
      af[mi] = *(const bf16x8*)&Alds[cur][wm * 32 + mi * 16 + lr][lg * 8];
#pragma unroll
    for (int ni = 0; ni < 2; ++ni)
      bfr[ni] = *(const bf16x8*)&Blds[cur][wn * 32 + ni * 16 + lr][lg * 8];
#pragma unroll
    for (int mi = 0; mi < 2; ++mi)
#pragma unroll
      for (int ni = 0; ni < 2; ++ni)
        acc[mi][ni] = MFMA16(af[mi], bfr[ni], acc[mi][ni]);
    __syncthreads();
  }
#undef QKV_STAGE_A

#pragma unroll
  for (int mi = 0; mi < 2; ++mi) {
#pragma unroll
    for (int ni = 0; ni < 2; ++ni) {
#pragma unroll
      for (int r = 0; r < 4; ++r) {
        int o = o0 + wm * 32 + mi * 16 + lg * 4 + r;
        int p = p0 + wn * 32 + ni * 16 + lr;
        float val = acc[mi][ni][r] + bias[o];
        if (o < 256) {
          qt[((size_t)b * 4096 + p) * 256 + o] = (bf16)val;
        } else if (o < 512) {
          kt[((size_t)b * 4096 + p) * 256 + (o - 256)] = (bf16)(val * SCALEK);
        } else {
          vcm[((size_t)b * 256 + (o - 512)) * 4096 + p] = (bf16)val;
        }
      }
    }
  }
}

// ---------------------------------------------------------------------------
// Kernel 3: flash attention (round-13 best, byte-identical).
// Swapped-operand 32x32x16, SW-pipelined fused cluster [QK(t+1) || PV(t)].
// QBLK=256 (8 waves), ring-2 (64 KB LDS). m==0 softmax, lane-local q.
// ---------------------------------------------------------------------------
template <int S>
__global__ __launch_bounds__(512, 2) void flash_attn(
    const bf16* __restrict__ qt, const bf16* __restrict__ kt,
    const bf16* __restrict__ vcm, bf16* __restrict__ Opart,
    float* __restrict__ l_g) {
  constexpr int NCOMBO = 4 * S;
  constexpr int CSH = (S == 4) ? 4 : (S == 2) ? 3 : 2;
  constexpr int NIT = (4096 / S) / 32;
  const int bid = blockIdx.x;
  const int combo = bid & (NCOMBO - 1);
  const int qtile = bid >> CSH;
  const int b = combo & 3;
  const int split = combo >> 2;
  const int i0 = qtile * 256;
  const int jbase = split * (4096 / S);

  __shared__ bf16 Klds[2][32][256];  // granule16 ^= (row&7) at stage
  __shared__ bf16 Vlds[2][256][32];  // granule16 ^= ((row>>2)&3) at stage
  const int tid = threadIdx.x;
  const int lane = tid & 63, w = tid >> 6;
  const int ln = lane & 31;   // q index (B col) / LDS row
  const int hv = lane >> 5;   // lane half
  const bf16* qb = qt + (size_t)b * 4096 * 256;
  const bf16* kb = kt + (size_t)b * 4096 * 256;
  const bf16* vb = vcm + (size_t)b * 256 * 4096;

  const int qrow = i0 + w * 32 + ln;
  bf16x8 qf[16];
#pragma unroll
  for (int ks = 0; ks < 16; ++ks)
    qf[ks] = *(const bf16x8*)(qb + (size_t)qrow * 256 + ks * 16 + hv * 8);

  int koff[2], voff[2];
#pragma unroll
  for (int it = 0; it < 2; ++it) {
    int chunk = tid + 512 * it;
    int krow = chunk >> 5;
    koff[it] = krow * 256 + ((((chunk & 31) ^ (krow & 7)) * 8));
    int vrow = chunk >> 2;
    voff[it] = vrow * 4096 + (((chunk & 3) ^ ((vrow >> 2) & 3)) * 8);
  }

#define STAGE_K(JT, BUF)                                                      \
  {                                                                           \
    const int j0s = jbase + (JT) * 32;                                        \
    _Pragma("unroll") for (int it = 0; it < 2; ++it) {                        \
      int chunk = tid + 512 * it;                                             \
      __builtin_amdgcn_global_load_lds(                                       \
          (gas_t)(const void*)(kb + (size_t)j0s * 256 + koff[it]),            \
          (las_t)(void*)(&Klds[BUF][0][0] + chunk * 8), 16, 0, 0);            \
    }                                                                         \
  }
#define STAGE_V(JT, BUF)                                                      \
  {                                                                           \
    const int j0s = jbase + (JT) * 32;                                        \
    _Pragma("unroll") for (int it = 0; it < 2; ++it) {                        \
      int chunk = tid + 512 * it;                                             \
      __builtin_amdgcn_global_load_lds(                                       \
          (gas_t)(const void*)(vb + (size_t)j0s + voff[it]),                  \
          (las_t)(void*)(&Vlds[BUF][0][0] + chunk * 8), 16, 0, 0);            \
    }                                                                         \
  }

  float llane = 0.f;
  f32x16 accO[8] = {};
  const int kswz = ln & 7;
  const int vswz = (ln >> 2) & 3;

  STAGE_K(0, 0);
  STAGE_V(0, 0);
  asm volatile("s_waitcnt vmcnt(0)" ::: "memory");
  __builtin_amdgcn_s_barrier();

  f32x16 a0 = {}, a1 = {};
#pragma unroll
  for (int ks = 0; ks < 8; ++ks) {
    bf16x8 kf0 = *(const bf16x8*)&Klds[0][ln][((2 * ks + hv) ^ kswz) * 8];
    bf16x8 kf1 =
        *(const bf16x8*)&Klds[0][ln][((2 * (ks + 8) + hv) ^ kswz) * 8];
    a0 = MFMA32(kf0, qf[ks], a0);
    a1 = MFMA32(kf1, qf[ks + 8], a1);
  }
  if (NIT > 1) STAGE_K(1, 1);

  for (int t = 0; t < NIT; ++t) {
    asm volatile("s_waitcnt vmcnt(0)" ::: "memory");
    __builtin_amdgcn_s_barrier();

    if (t + 1 < NIT) STAGE_V(t + 1, (t + 1) & 1);
    if (t + 2 < NIT) STAGE_K(t + 2, t & 1);

    float pv[16];
#pragma unroll
    for (int r = 0; r < 16; ++r) pv[r] = exp2f(a0[r] + a1[r]);
    llane += (((pv[0] + pv[1]) + (pv[2] + pv[3])) +
              ((pv[4] + pv[5]) + (pv[6] + pv[7]))) +
             (((pv[8] + pv[9]) + (pv[10] + pv[11])) +
              ((pv[12] + pv[13]) + (pv[14] + pv[15])));

    int pk[8];
#pragma unroll
    for (int q4 = 0; q4 < 8; ++q4)
      asm("v_cvt_pk_bf16_f32 %0, %1, %2"
          : "=v"(pk[q4])
          : "v"(pv[q4 * 2]), "v"(pv[q4 * 2 + 1]));
    bf16x8 pfrag[2];
#pragma unroll
    for (int s = 0; s < 2; ++s) {
      int xa = pk[s * 4 + 0], ya = pk[s * 4 + 2];
      int xb = pk[s * 4 + 1], yb = pk[s * 4 + 3];
      asm("v_permlane32_swap_b32 %0, %1" : "+v"(xa), "+v"(ya));
      asm("v_permlane32_swap_b32 %0, %1" : "+v"(xb), "+v"(yb));
      union { int i[4]; bf16x8 v; } u;
      u.i[0] = xa; u.i[1] = xb; u.i[2] = ya; u.i[3] = yb;
      pfrag[s] = u.v;
    }

    const bf16(*Kc)[256] = Klds[(t + 1) & 1];
    const bf16(*Vc)[32] = Vlds[t & 1];
    __builtin_amdgcn_s_setprio(1);
    if (t + 1 < NIT) {
      f32x16 n0 = {}, n1 = {};
#pragma unroll
      for (int u = 0; u < 8; ++u) {
        bf16x8 kf0 = *(const bf16x8*)&Kc[ln][((2 * u + hv) ^ kswz) * 8];
        n0 = MFMA32(kf0, qf[u], n0);
        bf16x8 kf1 =
            *(const bf16x8*)&Kc[ln][((2 * (u + 8) + hv) ^ kswz) * 8];
        n1 = MFMA32(kf1, qf[u + 8], n1);
        bf16x8 vf0 = *(const bf16x8*)&Vc[u * 32 + ln][((hv) ^ vswz) * 8];
        accO[u] = MFMA32(vf0, pfrag[0], accO[u]);
        bf16x8 vf1 = *(const bf16x8*)&Vc[u * 32 + ln][((2 + hv) ^ vswz) * 8];
        accO[u] = MFMA32(vf1, pfrag[1], accO[u]);
      }
      a0 = n0;
      a1 = n1;
    } else {
#pragma unroll
      for (int u = 0; u < 8; ++u) {
        bf16x8 vf0 = *(const bf16x8*)&Vc[u * 32 + ln][((hv) ^ vswz) * 8];
        accO[u] = MFMA32(vf0, pfrag[0], accO[u]);
        bf16x8 vf1 = *(const bf16x8*)&Vc[u * 32 + ln][((2 + hv) ^ vswz) * 8];
        accO[u] = MFMA32(vf1, pfrag[1], accO[u]);
      }
    }
    __builtin_amdgcn_s_setprio(0);
  }
#undef STAGE_K
#undef STAGE_V

  bf16* ob = Opart + ((size_t)(split * 4 + b) * 4096 + qrow) * 256;
#pragma unroll
  for (int cb = 0; cb < 8; ++cb) {
#pragma unroll
    for (int g = 0; g < 4; ++g) {
      int lo, hi;
      asm("v_cvt_pk_bf16_f32 %0, %1, %2"
          : "=v"(lo)
          : "v"(accO[cb][g * 4 + 0]), "v"(accO[cb][g * 4 + 1]));
      asm("v_cvt_pk_bf16_f32 %0, %1, %2"
          : "=v"(hi)
          : "v"(accO[cb][g * 4 + 2]), "v"(accO[cb][g * 4 + 3]));
      int2 val; val.x = lo; val.y = hi;
      *(int2*)(ob + cb * 32 + g * 8 + hv * 4) = val;
    }
  }
  {
    int xa = __float_as_int(llane);
    int ya = xa;
    asm("v_permlane32_swap_b32 %0, %1" : "+v"(xa), "+v"(ya));
    float ltot = __int_as_float(xa) + __int_as_float(ya);
    if (hv == 0)
      l_g[(size_t)(split * 4 + b) * 4096 + qrow] = ltot;
  }
}

// ---------------------------------------------------------------------------
// Kernel 4: proj GEMM + bias + residual, fused split-merge + normalize.
// ---------------------------------------------------------------------------
template <int S>
__global__ __launch_bounds__(256) void proj_fused(
    const bf16* __restrict__ Opart, const float* __restrict__ l_g,
    const float* __restrict__ w, const float* __restrict__ bias,
    const float* __restrict__ x, float* __restrict__ out) {
  const int b = blockIdx.y;
  const int p0 = blockIdx.x * 64;
  __shared__ bf16 Wlds[256][32];
  __shared__ bf16 Blds[64][32];
  __shared__ float Linv[64];
  const int tid = threadIdx.x;
  const int lane = tid & 63, wid = tid >> 6;
  const int lr = lane & 15, lg = lane >> 4;

  if (tid < 64) {
    float L = 0.f;
#pragma unroll
    for (int s = 0; s < S; ++s)
      L += l_g[(size_t)(s * 4 + b) * 4096 + p0 + tid];
    Linv[tid] = 1.f / L;
  }
  __syncthreads();

  const int pr = tid >> 2, c8b = (tid & 3) * 8;
  const float invp = Linv[pr];

  float4 wreg[4][2];
  bf16x8 breg[S];

#define PROJ_READ(K0)                                                         \
  {                                                                           \
    _Pragma("unroll") for (int it = 0; it < 4; ++it) {                        \
      int chunk = tid + 256 * it;                                             \
      int row = chunk >> 2, c8 = (chunk & 3) * 8;                             \
      const float* src = w + (size_t)row * 256 + (K0) + c8;                   \
      wreg[it][0] = *(const float4*)src;                                      \
      wreg[it][1] = *(const float4*)(src + 4);                                \
    }                                                                         \
    _Pragma("unroll") for (int s = 0; s < S; ++s) breg[s] =                   \
        *(const bf16x8*)(Opart +                                              \
                         ((size_t)(s * 4 + b) * 4096 + p0 + pr) * 256 +       \
                         (K0) + c8b);                                         \
  }
#define PROJ_WRITE()                                                          \
  {                                                                           \
    _Pragma("unroll") for (int it = 0; it < 4; ++it) {                        \
      int chunk = tid + 256 * it;                                             \
      int row = chunk >> 2, c8 = (chunk & 3) * 8;                             \
      bf16x8 bv;                                                              \
      bv[0] = (bf16)wreg[it][0].x; bv[1] = (bf16)wreg[it][0].y;               \
      bv[2] = (bf16)wreg[it][0].z; bv[3] = (bf16)wreg[it][0].w;               \
      bv[4] = (bf16)wreg[it][1].x; bv[5] = (bf16)wreg[it][1].y;               \
      bv[6] = (bf16)wreg[it][1].z; bv[7] = (bf16)wreg[it][1].w;               \
      *(bf16x8*)&Wlds[row][c8] = bv;                                          \
    }                                                                         \
    {                                                                         \
      float a8[8] = {};                                                       \
      _Pragma("unroll") for (int s = 0; s < S; ++s) {                         \
        _Pragma("unroll") for (int e = 0; e < 8; ++e) a8[e] +=                \
            (float)breg[s][e];                                                \
      }                                                                       \
      bf16x8 bv;                                                              \
      _Pragma("unroll") for (int e = 0; e < 8; ++e) bv[e] =                   \
          (bf16)(a8[e] * invp);                                               \
      *(bf16x8*)&Blds[pr][c8b] = bv;                                          \
    }                                                                         \
  }

  f32x4 acc[4][4] = {};

  PROJ_READ(0);
  PROJ_WRITE();
  __syncthreads();

  for (int k = 0; k < 8; ++k) {
    if (k < 7) PROJ_READ((k + 1) * 32);

    bf16x8 af[4], bfr[4];
#pragma unroll
    for (int mi = 0; mi < 4; ++mi)
      af[mi] = *(const bf16x8*)&Wlds[wid * 64 + mi * 16 + lr][lg * 8];
#pragma unroll
    for (int ni = 0; ni < 4; ++ni)
      bfr[ni] = *(const bf16x8*)&Blds[ni * 16 + lr][lg * 8];
#pragma unroll
    for (int mi = 0; mi < 4; ++mi)
#pragma unroll
      for (int ni = 0; ni < 4; ++ni)
        acc[mi][ni] = MFMA16(af[mi], bfr[ni], acc[mi][ni]);

    __syncthreads();
    if (k < 7) {
      PROJ_WRITE();
      __syncthreads();
    }
  }
#undef PROJ_READ
#undef PROJ_WRITE

#pragma unroll
  for (int mi = 0; mi < 4; ++mi) {
#pragma unroll
    for (int ni = 0; ni < 4; ++ni) {
#pragma unroll
      for (int r = 0; r < 4; ++r) {
        int o = wid * 64 + mi * 16 + lg * 4 + r;
        int p = p0 + ni * 16 + lr;
        size_t idx = ((size_t)b * 256 + o) * 4096 + p;
        out[idx] = acc[mi][ni][r] + bias[o] + x[idx];
      }
    }
  }
}

// ---------------------------------------------------------------------------
extern "C" void kernel_launch(void* const* d_in, const int* in_sizes, int n_in,
                              void* d_out, int out_size, void* d_ws,
                              size_t ws_size, hipStream_t stream) {
  (void)in_sizes; (void)n_in; (void)out_size;
  const float* x = (const float*)d_in[0];
  const float* gn_w = (const float*)d_in[1];
  const float* gn_b = (const float*)d_in[2];
  const float* qkv_w = (const float*)d_in[3];
  const float* qkv_b = (const float*)d_in[4];
  const float* proj_w = (const float*)d_in[5];
  const float* proj_b = (const float*)d_in[6];
  float* out = (float*)d_out;

  const size_t MB = 1024ull * 1024ull;
  char* ws = (char*)d_ws;
  bf16* h = (bf16*)(ws);
  bf16* qt = (bf16*)(ws + 8 * MB);
  bf16* kt = (bf16*)(ws + 16 * MB);
  bf16* vcm = (bf16*)(ws + 24 * MB);

  // pick split count by available scratch (S capped at 4: S=8 measured worse)
  int S;
  if (ws_size >= 32 * MB + 4 * 8 * MB + 4ull * 16384 * sizeof(float) + 8192)
    S = 4;
  else if (ws_size >= 32 * MB + 2 * 8 * MB + 2ull * 16384 * sizeof(float) + 8192)
    S = 2;
  else
    S = 1;

  bf16* Opart;
  float* l_g;
  bf16* qwb;  // bf16 copy of qkv_w (384 KB), parked where flash writes later
  if (S >= 2) {
    Opart = (bf16*)(ws + 32 * MB);
    l_g = (float*)(ws + 32 * MB + (size_t)S * 8 * MB);
    qwb = Opart;  // overwritten by flash AFTER qkv has consumed it
  } else {
    Opart = h;
    l_g = (float*)(ws + 32 * MB);
    qwb = (bf16*)(ws + 32 * MB + 512 * 1024);
  }
  float* pstats = l_g + (size_t)S * 16384;  // 1024 planes x 2 floats = 8 KB

  wcvt_kernel<<<192, 256, 0, stream>>>(qkv_w, qwb);
  gn_stats<<<1024, 256, 0, stream>>>(x, pstats);
  gn_apply<<<1024, 256, 0, stream>>>(x, pstats, gn_w, gn_b, h);
  qkv_gemm<<<dim3(64, 12, 4), 256, 0, stream>>>(h, qwb, qkv_b, qt, kt, vcm);
  if (S == 4) {
    flash_attn<4><<<16 * 16, 512, 0, stream>>>(qt, kt, vcm, Opart, l_g);
    proj_fused<4><<<dim3(64, 4), 256, 0, stream>>>(Opart, l_g, proj_w, proj_b,
                                                   x, out);
  } else if (S == 2) {
    flash_attn<2><<<16 * 8, 512, 0, stream>>>(qt, kt, vcm, Opart, l_g);
    proj_fused<2><<<dim3(64, 4), 256, 0, stream>>>(Opart, l_g, proj_w, proj_b,
                                                   x, out);
  } else {
    flash_attn<1><<<16 * 4, 512, 0, stream>>>(qt, kt, vcm, Opart, l_g);
    proj_fused<1><<<dim3(64, 4), 256, 0, stream>>>(Opart, l_g, proj_w, proj_b,
                                                   x, out);
  }
}

// Round 16
// 156.107 us; speedup vs baseline: 1.2191x; 1.0175x over previous
//
#include <hip/hip_runtime.h>
#include <hip/hip_bf16.h>
#include <math.h>

typedef __bf16 bf16;
typedef __bf16 bf16x8 __attribute__((ext_vector_type(8)));
typedef __bf16 bf16x4 __attribute__((ext_vector_type(4)));
typedef float f32x4 __attribute__((ext_vector_type(4)));
typedef float f32x16 __attribute__((ext_vector_type(16)));

#define MFMA16(a, b, c) __builtin_amdgcn_mfma_f32_16x16x32_bf16(a, b, c, 0, 0, 0)
#define MFMA32(a, b, c) __builtin_amdgcn_mfma_f32_32x32x16_bf16(a, b, c, 0, 0, 0)

// softmax scale (C^-0.5) * log2(e), folded into K values at qkv epilogue
#define SCALEK 0.09016844005555896f

typedef const __attribute__((address_space(1))) void* gas_t;
typedef __attribute__((address_space(3))) void* las_t;

// ---------------------------------------------------------------------------
// Kernel 1a: GroupNorm stats (+ fused qkv_w fp32->bf16 convert in blocks<192).
// 1024 blocks = one 4096-elem channel plane each; partial (sum,sumsq)/plane.
// ---------------------------------------------------------------------------
__global__ __launch_bounds__(256) void gn_stats(const float* __restrict__ x,
                                                float* __restrict__ pstats,
                                                const float* __restrict__ qw,
                                                bf16* __restrict__ qwb) {
  const int bid = blockIdx.x;                 // plane = b*256 + c
  const float* xp = x + (size_t)bid * 4096;
  const int tid = threadIdx.x;

  // fused wcvt: 768*256 = 196608 elems = 192 blocks x 256 thr x 4 elems
  if (bid < 192) {
    int t = bid * 256 + tid;
    float4 v = *(const float4*)(qw + (size_t)t * 4);
    bf16x4 o;
    o[0] = (bf16)v.x; o[1] = (bf16)v.y; o[2] = (bf16)v.z; o[3] = (bf16)v.w;
    *(bf16x4*)(qwb + (size_t)t * 4) = o;
  }

  float s = 0.f, ss = 0.f;
#pragma unroll
  for (int i = 0; i < 4; ++i) {
    float4 v = *(const float4*)(xp + tid * 4 + i * 1024);
    s += v.x + v.y + v.z + v.w;
    ss += v.x * v.x + v.y * v.y + v.z * v.z + v.w * v.w;
  }
#pragma unroll
  for (int off = 32; off; off >>= 1) {
    s += __shfl_down(s, off);
    ss += __shfl_down(ss, off);
  }
  __shared__ float red[8];
  if ((tid & 63) == 0) {
    red[(tid >> 6) * 2] = s;
    red[(tid >> 6) * 2 + 1] = ss;
  }
  __syncthreads();
  if (tid == 0) {
    pstats[bid * 2] = red[0] + red[2] + red[4] + red[6];
    pstats[bid * 2 + 1] = red[1] + red[3] + red[5] + red[7];
  }
}

// ---------------------------------------------------------------------------
// Kernel 1b: GroupNorm apply. 1024 blocks; each sums its group's 8 plane
// partials (uniform loads) and normalizes its plane -> h (bf16).
// ---------------------------------------------------------------------------
__global__ __launch_bounds__(256) void gn_apply(
    const float* __restrict__ x, const float* __restrict__ pstats,
    const float* __restrict__ gw, const float* __restrict__ gb,
    bf16* __restrict__ h) {
  const int bid = blockIdx.x;
  const int c = bid & 255;
  const int gbase = bid & ~7;                 // first plane of this group
  const float* xp = x + (size_t)bid * 4096;
  bf16* hp = h + (size_t)bid * 4096;
  const int tid = threadIdx.x;

  float s = 0.f, ss = 0.f;
#pragma unroll
  for (int i = 0; i < 8; ++i) {
    s += pstats[(gbase + i) * 2];
    ss += pstats[(gbase + i) * 2 + 1];
  }
  const float mean = s * (1.f / 32768.f);
  const float var = ss * (1.f / 32768.f) - mean * mean;
  const float rstd = rsqrtf(var + 1e-5f);
  const float a = gw[c] * rstd;
  const float b2 = gb[c] - mean * a;

#pragma unroll
  for (int i = 0; i < 4; ++i) {
    float4 v = *(const float4*)(xp + tid * 4 + i * 1024);
    bf16x4 o;
    o[0] = (bf16)(v.x * a + b2);
    o[1] = (bf16)(v.y * a + b2);
    o[2] = (bf16)(v.z * a + b2);
    o[3] = (bf16)(v.w * a + b2);
    *(bf16x4*)(hp + tid * 4 + i * 1024) = o;
  }
}

// ---------------------------------------------------------------------------
// Kernel 2: QKV GEMM (A = pre-converted bf16 w via global_load_lds, dbuf,
// 1 barrier/K-step). K output pre-scaled by SCALEK.
// ---------------------------------------------------------------------------
__global__ __launch_bounds__(256) void qkv_gemm(
    const bf16* __restrict__ h, const bf16* __restrict__ wb,
    const float* __restrict__ bias, bf16* __restrict__ qt,
    bf16* __restrict__ kt, bf16* __restrict__ vcm) {
  const int b = blockIdx.z;
  const int o0 = blockIdx.y * 64;
  const int p0 = blockIdx.x * 64;
  __shared__ bf16 Alds[2][64][32];
  __shared__ bf16 Blds[2][64][56];
  const int tid = threadIdx.x;
  const int lane = tid & 63, wid = tid >> 6;
  const int lr = lane & 15, lg = lane >> 4;
  const int wm = wid >> 1, wn = wid & 1;
  const bf16* hb = h + (size_t)b * 256 * 4096;

  const int arow = tid >> 2, ac8 = (tid & 3) * 8;
  const int bcc = tid >> 3, bp8 = (tid & 7) * 8;

#define QKV_STAGE_A(K0, BUF)                                                  \
  __builtin_amdgcn_global_load_lds(                                           \
      (gas_t)(const void*)(wb + (size_t)(o0 + arow) * 256 + (K0) + ac8),      \
      (las_t)(void*)(&Alds[BUF][0][0] + tid * 8), 16, 0, 0);

  f32x4 acc[2][2] = {};

  QKV_STAGE_A(0, 0);
  {
    bf16x8 v = *(const bf16x8*)(hb + (size_t)bcc * 4096 + p0 + bp8);
#pragma unroll
    for (int e = 0; e < 8; ++e) Blds[0][bp8 + e][bcc] = v[e];
  }
  __syncthreads();

  for (int k = 0; k < 8; ++k) {
    const int cur = k & 1, nb = cur ^ 1;
    if (k < 7) {
      QKV_STAGE_A((k + 1) * 32, nb);
      bf16x8 v =
          *(const bf16x8*)(hb + (size_t)((k + 1) * 32 + bcc) * 4096 + p0 + bp8);
#pragma unroll
      for (int e = 0; e < 8; ++e) Blds[nb][bp8 + e][bcc] = v[e];
    }
    bf16x8 af[2], bfr[2];
#pragma unroll
    for (int mi = 0; mi < 2; ++mi)
      af[mi] = *(const bf16x8*)&Alds[cur][wm * 32 + mi * 16 + lr][lg * 8];
#pragma unroll
    for (int ni = 0; ni < 2; ++ni)
      bfr[ni] = *(const bf16x8*)&Blds[cur][wn * 32 + ni * 16 + lr][lg * 8];
#pragma unroll
    for (int mi = 0; mi < 2; ++mi)
#pragma unroll
      for (int ni = 0; ni < 2; ++ni)
        acc[mi][ni] = MFMA16(af[mi], bfr[ni], acc[mi][ni]);
    __syncthreads();
  }
#undef QKV_STAGE_A

#pragma unroll
  for (int mi = 0; mi < 2; ++mi) {
#pragma unroll
    for (int ni = 0; ni < 2; ++ni) {
#pragma unroll
      for (int r = 0; r < 4; ++r) {
        int o = o0 + wm * 32 + mi * 16 + lg * 4 + r;
        int p = p0 + wn * 32 + ni * 16 + lr;
        float val = acc[mi][ni][r] + bias[o];
        if (o < 256) {
          qt[((size_t)b * 4096 + p) * 256 + o] = (bf16)val;
        } else if (o < 512) {
          kt[((size_t)b * 4096 + p) * 256 + (o - 256)] = (bf16)(val * SCALEK);
        } else {
          vcm[((size_t)b * 256 + (o - 512)) * 4096 + p] = (bf16)val;
        }
      }
    }
  }
}

// ---------------------------------------------------------------------------
// Kernel 3: flash attention. r13 structure + V ring-3 / counted vmcnt(2):
// cluster at t consumes K(t+1),V(t). Each iter issues K(t+2) THEN V(t+2);
// loop-top wait vmcnt(2) leaves the newest 2 (V, needed 2 iters later) in
// flight -> no full drain mid-loop (T4). LDS = 2x16K (K) + 3x16K (V) =
// 80 KB -> exactly 2 blocks/CU. m==0 softmax, lane-local. XCD-pinned.
// ---------------------------------------------------------------------------
template <int S>
__global__ __launch_bounds__(512, 2) void flash_attn(
    const bf16* __restrict__ qt, const bf16* __restrict__ kt,
    const bf16* __restrict__ vcm, bf16* __restrict__ Opart,
    float* __restrict__ l_g) {
  constexpr int NCOMBO = 4 * S;
  constexpr int CSH = (S == 4) ? 4 : (S == 2) ? 3 : 2;
  constexpr int NIT = (4096 / S) / 32;
  const int bid = blockIdx.x;
  const int combo = bid & (NCOMBO - 1);
  const int qtile = bid >> CSH;
  const int b = combo & 3;
  const int split = combo >> 2;
  const int i0 = qtile * 256;
  const int jbase = split * (4096 / S);

  __shared__ bf16 Klds[2][32][256];  // granule16 ^= (row&7) at stage
  __shared__ bf16 Vlds[3][256][32];  // granule16 ^= ((row>>2)&3) at stage
  const int tid = threadIdx.x;
  const int lane = tid & 63, w = tid >> 6;
  const int ln = lane & 31;   // q index (B col) / LDS row
  const int hv = lane >> 5;   // lane half
  const bf16* qb = qt + (size_t)b * 4096 * 256;
  const bf16* kb = kt + (size_t)b * 4096 * 256;
  const bf16* vb = vcm + (size_t)b * 256 * 4096;

  const int qrow = i0 + w * 32 + ln;
  bf16x8 qf[16];
#pragma unroll
  for (int ks = 0; ks < 16; ++ks)
    qf[ks] = *(const bf16x8*)(qb + (size_t)qrow * 256 + ks * 16 + hv * 8);

  int koff[2], voff[2];
#pragma unroll
  for (int it = 0; it < 2; ++it) {
    int chunk = tid + 512 * it;
    int krow = chunk >> 5;
    koff[it] = krow * 256 + ((((chunk & 31) ^ (krow & 7)) * 8));
    int vrow = chunk >> 2;
    voff[it] = vrow * 4096 + (((chunk & 3) ^ ((vrow >> 2) & 3)) * 8);
  }

#define STAGE_K(JT, BUF)                                                      \
  {                                                                           \
    const int j0s = jbase + (JT) * 32;                                        \
    _Pragma("unroll") for (int it = 0; it < 2; ++it) {                        \
      int chunk = tid + 512 * it;                                             \
      __builtin_amdgcn_global_load_lds(                                       \
          (gas_t)(const void*)(kb + (size_t)j0s * 256 + koff[it]),            \
          (las_t)(void*)(&Klds[BUF][0][0] + chunk * 8), 16, 0, 0);            \
    }                                                                         \
  }
#define STAGE_V(JT, BUF)                                                      \
  {                                                                           \
    const int j0s = jbase + (JT) * 32;                                        \
    _Pragma("unroll") for (int it = 0; it < 2; ++it) {                        \
      int chunk = tid + 512 * it;                                             \
      __builtin_amdgcn_global_load_lds(                                       \
          (gas_t)(const void*)(vb + (size_t)j0s + voff[it]),                  \
          (las_t)(void*)(&Vlds[BUF][0][0] + chunk * 8), 16, 0, 0);            \
    }                                                                         \
  }

  float llane = 0.f;
  f32x16 accO[8] = {};
  const int kswz = ln & 7;
  const int vswz = (ln >> 2) & 3;

  // prologue: tile 0 staged+landed; QK(0); then K(1), V(1) in flight
  STAGE_K(0, 0);
  STAGE_V(0, 0);
  asm volatile("s_waitcnt vmcnt(0)" ::: "memory");
  __builtin_amdgcn_s_barrier();

  f32x16 a0 = {}, a1 = {};
#pragma unroll
  for (int ks = 0; ks < 8; ++ks) {
    bf16x8 kf0 = *(const bf16x8*)&Klds[0][ln][((2 * ks + hv) ^ kswz) * 8];
    bf16x8 kf1 =
        *(const bf16x8*)&Klds[0][ln][((2 * (ks + 8) + hv) ^ kswz) * 8];
    a0 = MFMA32(kf0, qf[ks], a0);
    a1 = MFMA32(kf1, qf[ks + 8], a1);
  }
  if (NIT > 1) {
    STAGE_K(1, 1);
    STAGE_V(1, 1);
  }

  for (int t = 0; t < NIT; ++t) {
    // need K(t+1) and V(t) landed; the newest 2 loads (V issued last) may
    // stay in flight (counted wait - no full drain mid-loop).
    if (t + 1 < NIT)
      asm volatile("s_waitcnt vmcnt(2)" ::: "memory");
    else
      asm volatile("s_waitcnt vmcnt(0)" ::: "memory");
    __builtin_amdgcn_s_barrier();

    // prefetch two tiles ahead: K first (needed next iter), V second
    if (t + 2 < NIT) {
      STAGE_K(t + 2, t & 1);
      STAGE_V(t + 2, (t + 2) % 3);
    }

    // softmax(t): lane-local, m == 0
    float pv[16];
#pragma unroll
    for (int r = 0; r < 16; ++r) pv[r] = exp2f(a0[r] + a1[r]);
    llane += (((pv[0] + pv[1]) + (pv[2] + pv[3])) +
              ((pv[4] + pv[5]) + (pv[6] + pv[7]))) +
             (((pv[8] + pv[9]) + (pv[10] + pv[11])) +
              ((pv[12] + pv[13]) + (pv[14] + pv[15])));

    int pk[8];
#pragma unroll
    for (int q4 = 0; q4 < 8; ++q4)
      asm("v_cvt_pk_bf16_f32 %0, %1, %2"
          : "=v"(pk[q4])
          : "v"(pv[q4 * 2]), "v"(pv[q4 * 2 + 1]));
    bf16x8 pfrag[2];
#pragma unroll
    for (int s = 0; s < 2; ++s) {
      int xa = pk[s * 4 + 0], ya = pk[s * 4 + 2];
      int xb = pk[s * 4 + 1], yb = pk[s * 4 + 3];
      asm("v_permlane32_swap_b32 %0, %1" : "+v"(xa), "+v"(ya));
      asm("v_permlane32_swap_b32 %0, %1" : "+v"(xb), "+v"(yb));
      union { int i[4]; bf16x8 v; } u;
      u.i[0] = xa; u.i[1] = xb; u.i[2] = ya; u.i[3] = yb;
      pfrag[s] = u.v;
    }

    // fused MFMA cluster: QK(t+1) || PV(t)  (independent chains)
    const bf16(*Kc)[256] = Klds[(t + 1) & 1];
    const bf16(*Vc)[32] = Vlds[t % 3];
    __builtin_amdgcn_s_setprio(1);
    if (t + 1 < NIT) {
      f32x16 n0 = {}, n1 = {};
#pragma unroll
      for (int u = 0; u < 8; ++u) {
        bf16x8 kf0 = *(const bf16x8*)&Kc[ln][((2 * u + hv) ^ kswz) * 8];
        n0 = MFMA32(kf0, qf[u], n0);
        bf16x8 kf1 =
            *(const bf16x8*)&Kc[ln][((2 * (u + 8) + hv) ^ kswz) * 8];
        n1 = MFMA32(kf1, qf[u + 8], n1);
        bf16x8 vf0 = *(const bf16x8*)&Vc[u * 32 + ln][((hv) ^ vswz) * 8];
        accO[u] = MFMA32(vf0, pfrag[0], accO[u]);
        bf16x8 vf1 = *(const bf16x8*)&Vc[u * 32 + ln][((2 + hv) ^ vswz) * 8];
        accO[u] = MFMA32(vf1, pfrag[1], accO[u]);
      }
      a0 = n0;
      a1 = n1;
    } else {
#pragma unroll
      for (int u = 0; u < 8; ++u) {
        bf16x8 vf0 = *(const bf16x8*)&Vc[u * 32 + ln][((hv) ^ vswz) * 8];
        accO[u] = MFMA32(vf0, pfrag[0], accO[u]);
        bf16x8 vf1 = *(const bf16x8*)&Vc[u * 32 + ln][((2 + hv) ^ vswz) * 8];
        accO[u] = MFMA32(vf1, pfrag[1], accO[u]);
      }
    }
    __builtin_amdgcn_s_setprio(0);
  }
#undef STAGE_K
#undef STAGE_V

  bf16* ob = Opart + ((size_t)(split * 4 + b) * 4096 + qrow) * 256;
#pragma unroll
  for (int cb = 0; cb < 8; ++cb) {
#pragma unroll
    for (int g = 0; g < 4; ++g) {
      int lo, hi;
      asm("v_cvt_pk_bf16_f32 %0, %1, %2"
          : "=v"(lo)
          : "v"(accO[cb][g * 4 + 0]), "v"(accO[cb][g * 4 + 1]));
      asm("v_cvt_pk_bf16_f32 %0, %1, %2"
          : "=v"(hi)
          : "v"(accO[cb][g * 4 + 2]), "v"(accO[cb][g * 4 + 3]));
      int2 val; val.x = lo; val.y = hi;
      *(int2*)(ob + cb * 32 + g * 8 + hv * 4) = val;
    }
  }
  {
    int xa = __float_as_int(llane);
    int ya = xa;
    asm("v_permlane32_swap_b32 %0, %1" : "+v"(xa), "+v"(ya));
    float ltot = __int_as_float(xa) + __int_as_float(ya);
    if (hv == 0)
      l_g[(size_t)(split * 4 + b) * 4096 + qrow] = ltot;
  }
}

// ---------------------------------------------------------------------------
// Kernel 4: proj GEMM + bias + residual, fused split-merge + normalize.
// ---------------------------------------------------------------------------
template <int S>
__global__ __launch_bounds__(256) void proj_fused(
    const bf16* __restrict__ Opart, const float* __restrict__ l_g,
    const float* __restrict__ w, const float* __restrict__ bias,
    const float* __restrict__ x, float* __restrict__ out) {
  const int b = blockIdx.y;
  const int p0 = blockIdx.x * 64;
  __shared__ bf16 Wlds[256][32];
  __shared__ bf16 Blds[64][32];
  __shared__ float Linv[64];
  const int tid = threadIdx.x;
  const int lane = tid & 63, wid = tid >> 6;
  const int lr = lane & 15, lg = lane >> 4;

  if (tid < 64) {
    float L = 0.f;
#pragma unroll
    for (int s = 0; s < S; ++s)
      L += l_g[(size_t)(s * 4 + b) * 4096 + p0 + tid];
    Linv[tid] = 1.f / L;
  }
  __syncthreads();

  const int pr = tid >> 2, c8b = (tid & 3) * 8;
  const float invp = Linv[pr];

  float4 wreg[4][2];
  bf16x8 breg[S];

#define PROJ_READ(K0)                                                         \
  {                                                                           \
    _Pragma("unroll") for (int it = 0; it < 4; ++it) {                        \
      int chunk = tid + 256 * it;                                             \
      int row = chunk >> 2, c8 = (chunk & 3) * 8;                             \
      const float* src = w + (size_t)row * 256 + (K0) + c8;                   \
      wreg[it][0] = *(const float4*)src;                                      \
      wreg[it][1] = *(const float4*)(src + 4);                                \
    }                                                                         \
    _Pragma("unroll") for (int s = 0; s < S; ++s) breg[s] =                   \
        *(const bf16x8*)(Opart +                                              \
                         ((size_t)(s * 4 + b) * 4096 + p0 + pr) * 256 +       \
                         (K0) + c8b);                                         \
  }
#define PROJ_WRITE()                                                          \
  {                                                                           \
    _Pragma("unroll") for (int it = 0; it < 4; ++it) {                        \
      int chunk = tid + 256 * it;                                             \
      int row = chunk >> 2, c8 = (chunk & 3) * 8;                             \
      bf16x8 bv;                                                              \
      bv[0] = (bf16)wreg[it][0].x; bv[1] = (bf16)wreg[it][0].y;               \
      bv[2] = (bf16)wreg[it][0].z; bv[3] = (bf16)wreg[it][0].w;               \
      bv[4] = (bf16)wreg[it][1].x; bv[5] = (bf16)wreg[it][1].y;               \
      bv[6] = (bf16)wreg[it][1].z; bv[7] = (bf16)wreg[it][1].w;               \
      *(bf16x8*)&Wlds[row][c8] = bv;                                          \
    }                                                                         \
    {                                                                         \
      float a8[8] = {};                                                       \
      _Pragma("unroll") for (int s = 0; s < S; ++s) {                         \
        _Pragma("unroll") for (int e = 0; e < 8; ++e) a8[e] +=                \
            (float)breg[s][e];                                                \
      }                                                                       \
      bf16x8 bv;                                                              \
      _Pragma("unroll") for (int e = 0; e < 8; ++e) bv[e] =                   \
          (bf16)(a8[e] * invp);                                               \
      *(bf16x8*)&Blds[pr][c8b] = bv;                                          \
    }                                                                         \
  }

  f32x4 acc[4][4] = {};

  PROJ_READ(0);
  PROJ_WRITE();
  __syncthreads();

  for (int k = 0; k < 8; ++k) {
    if (k < 7) PROJ_READ((k + 1) * 32);

    bf16x8 af[4], bfr[4];
#pragma unroll
    for (int mi = 0; mi < 4; ++mi)
      af[mi] = *(const bf16x8*)&Wlds[wid * 64 + mi * 16 + lr][lg * 8];
#pragma unroll
    for (int ni = 0; ni < 4; ++ni)
      bfr[ni] = *(const bf16x8*)&Blds[ni * 16 + lr][lg * 8];
#pragma unroll
    for (int mi = 0; mi < 4; ++mi)
#pragma unroll
      for (int ni = 0; ni < 4; ++ni)
        acc[mi][ni] = MFMA16(af[mi], bfr[ni], acc[mi][ni]);

    __syncthreads();
    if (k < 7) {
      PROJ_WRITE();
      __syncthreads();
    }
  }
#undef PROJ_READ
#undef PROJ_WRITE

#pragma unroll
  for (int mi = 0; mi < 4; ++mi) {
#pragma unroll
    for (int ni = 0; ni < 4; ++ni) {
#pragma unroll
      for (int r = 0; r < 4; ++r) {
        int o = wid * 64 + mi * 16 + lg * 4 + r;
        int p = p0 + ni * 16 + lr;
        size_t idx = ((size_t)b * 256 + o) * 4096 + p;
        out[idx] = acc[mi][ni][r] + bias[o] + x[idx];
      }
    }
  }
}

// ---------------------------------------------------------------------------
extern "C" void kernel_launch(void* const* d_in, const int* in_sizes, int n_in,
                              void* d_out, int out_size, void* d_ws,
                              size_t ws_size, hipStream_t stream) {
  (void)in_sizes; (void)n_in; (void)out_size;
  const float* x = (const float*)d_in[0];
  const float* gn_w = (const float*)d_in[1];
  const float* gn_b = (const float*)d_in[2];
  const float* qkv_w = (const float*)d_in[3];
  const float* qkv_b = (const float*)d_in[4];
  const float* proj_w = (const float*)d_in[5];
  const float* proj_b = (const float*)d_in[6];
  float* out = (float*)d_out;

  const size_t MB = 1024ull * 1024ull;
  char* ws = (char*)d_ws;
  bf16* h = (bf16*)(ws);
  bf16* qt = (bf16*)(ws + 8 * MB);
  bf16* kt = (bf16*)(ws + 16 * MB);
  bf16* vcm = (bf16*)(ws + 24 * MB);

  // pick split count by available scratch (S capped at 4: S=8 measured worse)
  int S;
  if (ws_size >= 32 * MB + 4 * 8 * MB + 4ull * 16384 * sizeof(float) + 8192)
    S = 4;
  else if (ws_size >= 32 * MB + 2 * 8 * MB + 2ull * 16384 * sizeof(float) + 8192)
    S = 2;
  else
    S = 1;

  bf16* Opart;
  float* l_g;
  bf16* qwb;  // bf16 copy of qkv_w (384 KB), parked where flash writes later
  if (S >= 2) {
    Opart = (bf16*)(ws + 32 * MB);
    l_g = (float*)(ws + 32 * MB + (size_t)S * 8 * MB);
    qwb = Opart;  // overwritten by flash AFTER qkv has consumed it
  } else {
    Opart = h;
    l_g = (float*)(ws + 32 * MB);
    qwb = (bf16*)(ws + 32 * MB + 512 * 1024);
  }
  float* pstats = l_g + (size_t)S * 16384;  // 1024 planes x 2 floats = 8 KB

  gn_stats<<<1024, 256, 0, stream>>>(x, pstats, qkv_w, qwb);
  gn_apply<<<1024, 256, 0, stream>>>(x, pstats, gn_w, gn_b, h);
  qkv_gemm<<<dim3(64, 12, 4), 256, 0, stream>>>(h, qwb, qkv_b, qt, kt, vcm);
  if (S == 4) {
    flash_attn<4><<<16 * 16, 512, 0, stream>>>(qt, kt, vcm, Opart, l_g);
    proj_fused<4><<<dim3(64, 4), 256, 0, stream>>>(Opart, l_g, proj_w, proj_b,
                                                   x, out);
  } else if (S == 2) {
    flash_attn<2><<<16 * 8, 512, 0, stream>>>(qt, kt, vcm, Opart, l_g);
    proj_fused<2><<<dim3(64, 4), 256, 0, stream>>>(Opart, l_g, proj_w, proj_b,
                                                   x, out);
  } else {
    flash_attn<1><<<16 * 4, 512, 0, stream>>>(qt, kt, vcm, Opart, l_g);
    proj_fused<1><<<dim3(64, 4), 256, 0, stream>>>(Opart, l_g, proj_w, proj_b,
                                                   x, out);
  }
}

// Round 17
// 154.629 us; speedup vs baseline: 1.2307x; 1.0096x over previous
//
#include <hip/hip_runtime.h>
#include <hip/hip_bf16.h>
#include <math.h>

typedef __bf16 bf16;
typedef __bf16 bf16x8 __attribute__((ext_vector_type(8)));
typedef __bf16 bf16x4 __attribute__((ext_vector_type(4)));
typedef float f32x4 __attribute__((ext_vector_type(4)));
typedef float f32x16 __attribute__((ext_vector_type(16)));

#define MFMA16(a, b, c) __builtin_amdgcn_mfma_f32_16x16x32_bf16(a, b, c, 0, 0, 0)
#define MFMA32(a, b, c) __builtin_amdgcn_mfma_f32_32x32x16_bf16(a, b, c, 0, 0, 0)

// softmax scale (C^-0.5) * log2(e), folded into K values at qkv epilogue
#define SCALEK 0.09016844005555896f

typedef const __attribute__((address_space(1))) void* gas_t;
typedef __attribute__((address_space(3))) void* las_t;

// ---------------------------------------------------------------------------
// Kernel 1a: GroupNorm stats (+ fused qkv_w fp32->bf16 convert in blocks<192).
// 1024 blocks = one 4096-elem channel plane each; partial (sum,sumsq)/plane.
// ---------------------------------------------------------------------------
__global__ __launch_bounds__(256) void gn_stats(const float* __restrict__ x,
                                                float* __restrict__ pstats,
                                                const float* __restrict__ qw,
                                                bf16* __restrict__ qwb) {
  const int bid = blockIdx.x;                 // plane = b*256 + c
  const float* xp = x + (size_t)bid * 4096;
  const int tid = threadIdx.x;

  // fused wcvt: 768*256 = 196608 elems = 192 blocks x 256 thr x 4 elems
  if (bid < 192) {
    int t = bid * 256 + tid;
    float4 v = *(const float4*)(qw + (size_t)t * 4);
    bf16x4 o;
    o[0] = (bf16)v.x; o[1] = (bf16)v.y; o[2] = (bf16)v.z; o[3] = (bf16)v.w;
    *(bf16x4*)(qwb + (size_t)t * 4) = o;
  }

  float s = 0.f, ss = 0.f;
#pragma unroll
  for (int i = 0; i < 4; ++i) {
    float4 v = *(const float4*)(xp + tid * 4 + i * 1024);
    s += v.x + v.y + v.z + v.w;
    ss += v.x * v.x + v.y * v.y + v.z * v.z + v.w * v.w;
  }
#pragma unroll
  for (int off = 32; off; off >>= 1) {
    s += __shfl_down(s, off);
    ss += __shfl_down(ss, off);
  }
  __shared__ float red[8];
  if ((tid & 63) == 0) {
    red[(tid >> 6) * 2] = s;
    red[(tid >> 6) * 2 + 1] = ss;
  }
  __syncthreads();
  if (tid == 0) {
    pstats[bid * 2] = red[0] + red[2] + red[4] + red[6];
    pstats[bid * 2 + 1] = red[1] + red[3] + red[5] + red[7];
  }
}

// ---------------------------------------------------------------------------
// Kernel 1b: GroupNorm apply. 1024 blocks; each sums its group's 8 plane
// partials (uniform loads) and normalizes its plane -> h (bf16).
// ---------------------------------------------------------------------------
__global__ __launch_bounds__(256) void gn_apply(
    const float* __restrict__ x, const float* __restrict__ pstats,
    const float* __restrict__ gw, const float* __restrict__ gb,
    bf16* __restrict__ h) {
  const int bid = blockIdx.x;
  const int c = bid & 255;
  const int gbase = bid & ~7;                 // first plane of this group
  const float* xp = x + (size_t)bid * 4096;
  bf16* hp = h + (size_t)bid * 4096;
  const int tid = threadIdx.x;

  float s = 0.f, ss = 0.f;
#pragma unroll
  for (int i = 0; i < 8; ++i) {
    s += pstats[(gbase + i) * 2];
    ss += pstats[(gbase + i) * 2 + 1];
  }
  const float mean = s * (1.f / 32768.f);
  const float var = ss * (1.f / 32768.f) - mean * mean;
  const float rstd = rsqrtf(var + 1e-5f);
  const float a = gw[c] * rstd;
  const float b2 = gb[c] - mean * a;

#pragma unroll
  for (int i = 0; i < 4; ++i) {
    float4 v = *(const float4*)(xp + tid * 4 + i * 1024);
    bf16x4 o;
    o[0] = (bf16)(v.x * a + b2);
    o[1] = (bf16)(v.y * a + b2);
    o[2] = (bf16)(v.z * a + b2);
    o[3] = (bf16)(v.w * a + b2);
    *(bf16x4*)(hp + tid * 4 + i * 1024) = o;
  }
}

// ---------------------------------------------------------------------------
// Kernel 2: QKV GEMM (A = pre-converted bf16 w via global_load_lds, dbuf,
// 1 barrier/K-step). K output pre-scaled by SCALEK.
// ---------------------------------------------------------------------------
__global__ __launch_bounds__(256) void qkv_gemm(
    const bf16* __restrict__ h, const bf16* __restrict__ wb,
    const float* __restrict__ bias, bf16* __restrict__ qt,
    bf16* __restrict__ kt, bf16* __restrict__ vcm) {
  const int b = blockIdx.z;
  const int o0 = blockIdx.y * 64;
  const int p0 = blockIdx.x * 64;
  __shared__ bf16 Alds[2][64][32];
  __shared__ bf16 Blds[2][64][56];
  const int tid = threadIdx.x;
  const int lane = tid & 63, wid = tid >> 6;
  const int lr = lane & 15, lg = lane >> 4;
  const int wm = wid >> 1, wn = wid & 1;
  const bf16* hb = h + (size_t)b * 256 * 4096;

  const int arow = tid >> 2, ac8 = (tid & 3) * 8;
  const int bcc = tid >> 3, bp8 = (tid & 7) * 8;

#define QKV_STAGE_A(K0, BUF)                                                  \
  __builtin_amdgcn_global_load_lds(                                           \
      (gas_t)(const void*)(wb + (size_t)(o0 + arow) * 256 + (K0) + ac8),      \
      (las_t)(void*)(&Alds[BUF][0][0] + tid * 8), 16, 0, 0);

  f32x4 acc[2][2] = {};

  QKV_STAGE_A(0, 0);
  {
    bf16x8 v = *(const bf16x8*)(hb + (size_t)bcc * 4096 + p0 + bp8);
#pragma unroll
    for (int e = 0; e < 8; ++e) Blds[0][bp8 + e][bcc] = v[e];
  }
  __syncthreads();

  for (int k = 0; k < 8; ++k) {
    const int cur = k & 1, nb = cur ^ 1;
    if (k < 7) {
      QKV_STAGE_A((k + 1) * 32, nb);
      bf16x8 v =
          *(const bf16x8*)(hb + (size_t)((k + 1) * 32 + bcc) * 4096 + p0 + bp8);
#pragma unroll
      for (int e = 0; e < 8; ++e) Blds[nb][bp8 + e][bcc] = v[e];
    }
    bf16x8 af[2], bfr[2];
#pragma unroll
    for (int mi = 0; mi < 2; ++mi)
      af[mi] = *(const bf16x8*)&Alds[cur][wm * 32 + mi * 16 + lr][lg * 8];
#pragma unroll
    for (int ni = 0; ni < 2; ++ni)
      bfr[ni] = *(const bf16x8*)&Blds[cur][wn * 32 + ni * 16 + lr][lg * 8];
#pragma unroll
    for (int mi = 0; mi < 2; ++mi)
#pragma unroll
      for (int ni = 0; ni < 2; ++ni)
        acc[mi][ni] = MFMA16(af[mi], bfr[ni], acc[mi][ni]);
    __syncthreads();
  }
#undef QKV_STAGE_A

#pragma unroll
  for (int mi = 0; mi < 2; ++mi) {
#pragma unroll
    for (int ni = 0; ni < 2; ++ni) {
#pragma unroll
      for (int r = 0; r < 4; ++r) {
        int o = o0 + wm * 32 + mi * 16 + lg * 4 + r;
        int p = p0 + wn * 32 + ni * 16 + lr;
        float val = acc[mi][ni][r] + bias[o];
        if (o < 256) {
          qt[((size_t)b * 4096 + p) * 256 + o] = (bf16)val;
        } else if (o < 512) {
          kt[((size_t)b * 4096 + p) * 256 + (o - 256)] = (bf16)(val * SCALEK);
        } else {
          vcm[((size_t)b * 256 + (o - 512)) * 4096 + p] = (bf16)val;
        }
      }
    }
  }
}

// ---------------------------------------------------------------------------
// Kernel 3: flash attention (round-13 best variant, restored byte-exact).
// Swapped-operand 32x32x16, SW-pipelined fused cluster [QK(t+1) || PV(t)].
// QBLK=256 (8 waves), ring-2 (64 KB LDS), vmcnt(0)+barrier per tile.
// m==0 softmax (log2 domain), lane-local q=lane&31. XCD-pinned combos.
// ---------------------------------------------------------------------------
template <int S>
__global__ __launch_bounds__(512, 2) void flash_attn(
    const bf16* __restrict__ qt, const bf16* __restrict__ kt,
    const bf16* __restrict__ vcm, bf16* __restrict__ Opart,
    float* __restrict__ l_g) {
  constexpr int NCOMBO = 4 * S;
  constexpr int CSH = (S == 4) ? 4 : (S == 2) ? 3 : 2;
  constexpr int NIT = (4096 / S) / 32;
  const int bid = blockIdx.x;
  const int combo = bid & (NCOMBO - 1);
  const int qtile = bid >> CSH;
  const int b = combo & 3;
  const int split = combo >> 2;
  const int i0 = qtile * 256;
  const int jbase = split * (4096 / S);

  __shared__ bf16 Klds[2][32][256];  // granule16 ^= (row&7) at stage
  __shared__ bf16 Vlds[2][256][32];  // granule16 ^= ((row>>2)&3) at stage
  const int tid = threadIdx.x;
  const int lane = tid & 63, w = tid >> 6;
  const int ln = lane & 31;   // q index (B col) / LDS row
  const int hv = lane >> 5;   // lane half
  const bf16* qb = qt + (size_t)b * 4096 * 256;
  const bf16* kb = kt + (size_t)b * 4096 * 256;
  const bf16* vb = vcm + (size_t)b * 256 * 4096;

  const int qrow = i0 + w * 32 + ln;
  bf16x8 qf[16];
#pragma unroll
  for (int ks = 0; ks < 16; ++ks)
    qf[ks] = *(const bf16x8*)(qb + (size_t)qrow * 256 + ks * 16 + hv * 8);

  int koff[2], voff[2];
#pragma unroll
  for (int it = 0; it < 2; ++it) {
    int chunk = tid + 512 * it;
    int krow = chunk >> 5;
    koff[it] = krow * 256 + ((((chunk & 31) ^ (krow & 7)) * 8));
    int vrow = chunk >> 2;
    voff[it] = vrow * 4096 + (((chunk & 3) ^ ((vrow >> 2) & 3)) * 8);
  }

#define STAGE_K(JT, BUF)                                                      \
  {                                                                           \
    const int j0s = jbase + (JT) * 32;                                        \
    _Pragma("unroll") for (int it = 0; it < 2; ++it) {                        \
      int chunk = tid + 512 * it;                                             \
      __builtin_amdgcn_global_load_lds(                                       \
          (gas_t)(const void*)(kb + (size_t)j0s * 256 + koff[it]),            \
          (las_t)(void*)(&Klds[BUF][0][0] + chunk * 8), 16, 0, 0);            \
    }                                                                         \
  }
#define STAGE_V(JT, BUF)                                                      \
  {                                                                           \
    const int j0s = jbase + (JT) * 32;                                        \
    _Pragma("unroll") for (int it = 0; it < 2; ++it) {                        \
      int chunk = tid + 512 * it;                                             \
      __builtin_amdgcn_global_load_lds(                                       \
          (gas_t)(const void*)(vb + (size_t)j0s + voff[it]),                  \
          (las_t)(void*)(&Vlds[BUF][0][0] + chunk * 8), 16, 0, 0);            \
    }                                                                         \
  }

  float llane = 0.f;
  f32x16 accO[8] = {};
  const int kswz = ln & 7;
  const int vswz = (ln >> 2) & 3;

  STAGE_K(0, 0);
  STAGE_V(0, 0);
  asm volatile("s_waitcnt vmcnt(0)" ::: "memory");
  __builtin_amdgcn_s_barrier();

  f32x16 a0 = {}, a1 = {};
#pragma unroll
  for (int ks = 0; ks < 8; ++ks) {
    bf16x8 kf0 = *(const bf16x8*)&Klds[0][ln][((2 * ks + hv) ^ kswz) * 8];
    bf16x8 kf1 =
        *(const bf16x8*)&Klds[0][ln][((2 * (ks + 8) + hv) ^ kswz) * 8];
    a0 = MFMA32(kf0, qf[ks], a0);
    a1 = MFMA32(kf1, qf[ks + 8], a1);
  }
  if (NIT > 1) STAGE_K(1, 1);

  for (int t = 0; t < NIT; ++t) {
    asm volatile("s_waitcnt vmcnt(0)" ::: "memory");
    __builtin_amdgcn_s_barrier();

    if (t + 1 < NIT) STAGE_V(t + 1, (t + 1) & 1);
    if (t + 2 < NIT) STAGE_K(t + 2, t & 1);

    float pv[16];
#pragma unroll
    for (int r = 0; r < 16; ++r) pv[r] = exp2f(a0[r] + a1[r]);
    llane += (((pv[0] + pv[1]) + (pv[2] + pv[3])) +
              ((pv[4] + pv[5]) + (pv[6] + pv[7]))) +
             (((pv[8] + pv[9]) + (pv[10] + pv[11])) +
              ((pv[12] + pv[13]) + (pv[14] + pv[15])));

    int pk[8];
#pragma unroll
    for (int q4 = 0; q4 < 8; ++q4)
      asm("v_cvt_pk_bf16_f32 %0, %1, %2"
          : "=v"(pk[q4])
          : "v"(pv[q4 * 2]), "v"(pv[q4 * 2 + 1]));
    bf16x8 pfrag[2];
#pragma unroll
    for (int s = 0; s < 2; ++s) {
      int xa = pk[s * 4 + 0], ya = pk[s * 4 + 2];
      int xb = pk[s * 4 + 1], yb = pk[s * 4 + 3];
      asm("v_permlane32_swap_b32 %0, %1" : "+v"(xa), "+v"(ya));
      asm("v_permlane32_swap_b32 %0, %1" : "+v"(xb), "+v"(yb));
      union { int i[4]; bf16x8 v; } u;
      u.i[0] = xa; u.i[1] = xb; u.i[2] = ya; u.i[3] = yb;
      pfrag[s] = u.v;
    }

    const bf16(*Kc)[256] = Klds[(t + 1) & 1];
    const bf16(*Vc)[32] = Vlds[t & 1];
    __builtin_amdgcn_s_setprio(1);
    if (t + 1 < NIT) {
      f32x16 n0 = {}, n1 = {};
#pragma unroll
      for (int u = 0; u < 8; ++u) {
        bf16x8 kf0 = *(const bf16x8*)&Kc[ln][((2 * u + hv) ^ kswz) * 8];
        n0 = MFMA32(kf0, qf[u], n0);
        bf16x8 kf1 =
            *(const bf16x8*)&Kc[ln][((2 * (u + 8) + hv) ^ kswz) * 8];
        n1 = MFMA32(kf1, qf[u + 8], n1);
        bf16x8 vf0 = *(const bf16x8*)&Vc[u * 32 + ln][((hv) ^ vswz) * 8];
        accO[u] = MFMA32(vf0, pfrag[0], accO[u]);
        bf16x8 vf1 = *(const bf16x8*)&Vc[u * 32 + ln][((2 + hv) ^ vswz) * 8];
        accO[u] = MFMA32(vf1, pfrag[1], accO[u]);
      }
      a0 = n0;
      a1 = n1;
    } else {
#pragma unroll
      for (int u = 0; u < 8; ++u) {
        bf16x8 vf0 = *(const bf16x8*)&Vc[u * 32 + ln][((hv) ^ vswz) * 8];
        accO[u] = MFMA32(vf0, pfrag[0], accO[u]);
        bf16x8 vf1 = *(const bf16x8*)&Vc[u * 32 + ln][((2 + hv) ^ vswz) * 8];
        accO[u] = MFMA32(vf1, pfrag[1], accO[u]);
      }
    }
    __builtin_amdgcn_s_setprio(0);
  }
#undef STAGE_K
#undef STAGE_V

  bf16* ob = Opart + ((size_t)(split * 4 + b) * 4096 + qrow) * 256;
#pragma unroll
  for (int cb = 0; cb < 8; ++cb) {
#pragma unroll
    for (int g = 0; g < 4; ++g) {
      int lo, hi;
      asm("v_cvt_pk_bf16_f32 %0, %1, %2"
          : "=v"(lo)
          : "v"(accO[cb][g * 4 + 0]), "v"(accO[cb][g * 4 + 1]));
      asm("v_cvt_pk_bf16_f32 %0, %1, %2"
          : "=v"(hi)
          : "v"(accO[cb][g * 4 + 2]), "v"(accO[cb][g * 4 + 3]));
      int2 val; val.x = lo; val.y = hi;
      *(int2*)(ob + cb * 32 + g * 8 + hv * 4) = val;
    }
  }
  {
    int xa = __float_as_int(llane);
    int ya = xa;
    asm("v_permlane32_swap_b32 %0, %1" : "+v"(xa), "+v"(ya));
    float ltot = __int_as_float(xa) + __int_as_float(ya);
    if (hv == 0)
      l_g[(size_t)(split * 4 + b) * 4096 + qrow] = ltot;
  }
}

// ---------------------------------------------------------------------------
// Kernel 4: proj GEMM + bias + residual, fused split-merge + normalize.
// ---------------------------------------------------------------------------
template <int S>
__global__ __launch_bounds__(256) void proj_fused(
    const bf16* __restrict__ Opart, const float* __restrict__ l_g,
    const float* __restrict__ w, const float* __restrict__ bias,
    const float* __restrict__ x, float* __restrict__ out) {
  const int b = blockIdx.y;
  const int p0 = blockIdx.x * 64;
  __shared__ bf16 Wlds[256][32];
  __shared__ bf16 Blds[64][32];
  __shared__ float Linv[64];
  const int tid = threadIdx.x;
  const int lane = tid & 63, wid = tid >> 6;
  const int lr = lane & 15, lg = lane >> 4;

  if (tid < 64) {
    float L = 0.f;
#pragma unroll
    for (int s = 0; s < S; ++s)
      L += l_g[(size_t)(s * 4 + b) * 4096 + p0 + tid];
    Linv[tid] = 1.f / L;
  }
  __syncthreads();

  const int pr = tid >> 2, c8b = (tid & 3) * 8;
  const float invp = Linv[pr];

  float4 wreg[4][2];
  bf16x8 breg[S];

#define PROJ_READ(K0)                                                         \
  {                                                                           \
    _Pragma("unroll") for (int it = 0; it < 4; ++it) {                        \
      int chunk = tid + 256 * it;                                             \
      int row = chunk >> 2, c8 = (chunk & 3) * 8;                             \
      const float* src = w + (size_t)row * 256 + (K0) + c8;                   \
      wreg[it][0] = *(const float4*)src;                                      \
      wreg[it][1] = *(const float4*)(src + 4);                                \
    }                                                                         \
    _Pragma("unroll") for (int s = 0; s < S; ++s) breg[s] =                   \
        *(const bf16x8*)(Opart +                                              \
                         ((size_t)(s * 4 + b) * 4096 + p0 + pr) * 256 +       \
                         (K0) + c8b);                                         \
  }
#define PROJ_WRITE()                                                          \
  {                                                                           \
    _Pragma("unroll") for (int it = 0; it < 4; ++it) {                        \
      int chunk = tid + 256 * it;                                             \
      int row = chunk >> 2, c8 = (chunk & 3) * 8;                             \
      bf16x8 bv;                                                              \
      bv[0] = (bf16)wreg[it][0].x; bv[1] = (bf16)wreg[it][0].y;               \
      bv[2] = (bf16)wreg[it][0].z; bv[3] = (bf16)wreg[it][0].w;               \
      bv[4] = (bf16)wreg[it][1].x; bv[5] = (bf16)wreg[it][1].y;               \
      bv[6] = (bf16)wreg[it][1].z; bv[7] = (bf16)wreg[it][1].w;               \
      *(bf16x8*)&Wlds[row][c8] = bv;                                          \
    }                                                                         \
    {                                                                         \
      float a8[8] = {};                                                       \
      _Pragma("unroll") for (int s = 0; s < S; ++s) {                         \
        _Pragma("unroll") for (int e = 0; e < 8; ++e) a8[e] +=                \
            (float)breg[s][e];                                                \
      }                                                                       \
      bf16x8 bv;                                                              \
      _Pragma("unroll") for (int e = 0; e < 8; ++e) bv[e] =                   \
          (bf16)(a8[e] * invp);                                               \
      *(bf16x8*)&Blds[pr][c8b] = bv;                                          \
    }                                                                         \
  }

  f32x4 acc[4][4] = {};

  PROJ_READ(0);
  PROJ_WRITE();
  __syncthreads();

  for (int k = 0; k < 8; ++k) {
    if (k < 7) PROJ_READ((k + 1) * 32);

    bf16x8 af[4], bfr[4];
#pragma unroll
    for (int mi = 0; mi < 4; ++mi)
      af[mi] = *(const bf16x8*)&Wlds[wid * 64 + mi * 16 + lr][lg * 8];
#pragma unroll
    for (int ni = 0; ni < 4; ++ni)
      bfr[ni] = *(const bf16x8*)&Blds[ni * 16 + lr][lg * 8];
#pragma unroll
    for (int mi = 0; mi < 4; ++mi)
#pragma unroll
      for (int ni = 0; ni < 4; ++ni)
        acc[mi][ni] = MFMA16(af[mi], bfr[ni], acc[mi][ni]);

    __syncthreads();
    if (k < 7) {
      PROJ_WRITE();
      __syncthreads();
    }
  }
#undef PROJ_READ
#undef PROJ_WRITE

#pragma unroll
  for (int mi = 0; mi < 4; ++mi) {
#pragma unroll
    for (int ni = 0; ni < 4; ++ni) {
#pragma unroll
      for (int r = 0; r < 4; ++r) {
        int o = wid * 64 + mi * 16 + lg * 4 + r;
        int p = p0 + ni * 16 + lr;
        size_t idx = ((size_t)b * 256 + o) * 4096 + p;
        out[idx] = acc[mi][ni][r] + bias[o] + x[idx];
      }
    }
  }
}

// ---------------------------------------------------------------------------
extern "C" void kernel_launch(void* const* d_in, const int* in_sizes, int n_in,
                              void* d_out, int out_size, void* d_ws,
                              size_t ws_size, hipStream_t stream) {
  (void)in_sizes; (void)n_in; (void)out_size;
  const float* x = (const float*)d_in[0];
  const float* gn_w = (const float*)d_in[1];
  const float* gn_b = (const float*)d_in[2];
  const float* qkv_w = (const float*)d_in[3];
  const float* qkv_b = (const float*)d_in[4];
  const float* proj_w = (const float*)d_in[5];
  const float* proj_b = (const float*)d_in[6];
  float* out = (float*)d_out;

  const size_t MB = 1024ull * 1024ull;
  char* ws = (char*)d_ws;
  bf16* h = (bf16*)(ws);
  bf16* qt = (bf16*)(ws + 8 * MB);
  bf16* kt = (bf16*)(ws + 16 * MB);
  bf16* vcm = (bf16*)(ws + 24 * MB);

  // pick split count by available scratch (S capped at 4: S=8 measured worse)
  int S;
  if (ws_size >= 32 * MB + 4 * 8 * MB + 4ull * 16384 * sizeof(float) + 8192)
    S = 4;
  else if (ws_size >= 32 * MB + 2 * 8 * MB + 2ull * 16384 * sizeof(float) + 8192)
    S = 2;
  else
    S = 1;

  bf16* Opart;
  float* l_g;
  bf16* qwb;  // bf16 copy of qkv_w (384 KB), parked where flash writes later
  if (S >= 2) {
    Opart = (bf16*)(ws + 32 * MB);
    l_g = (float*)(ws + 32 * MB + (size_t)S * 8 * MB);
    qwb = Opart;  // overwritten by flash AFTER qkv has consumed it
  } else {
    Opart = h;
    l_g = (float*)(ws + 32 * MB);
    qwb = (bf16*)(ws + 32 * MB + 512 * 1024);
  }
  float* pstats = l_g + (size_t)S * 16384;  // 1024 planes x 2 floats = 8 KB

  gn_stats<<<1024, 256, 0, stream>>>(x, pstats, qkv_w, qwb);
  gn_apply<<<1024, 256, 0, stream>>>(x, pstats, gn_w, gn_b, h);
  qkv_gemm<<<dim3(64, 12, 4), 256, 0, stream>>>(h, qwb, qkv_b, qt, kt, vcm);
  if (S == 4) {
    flash_attn<4><<<16 * 16, 512, 0, stream>>>(qt, kt, vcm, Opart, l_g);
    proj_fused<4><<<dim3(64, 4), 256, 0, stream>>>(Opart, l_g, proj_w, proj_b,
                                                   x, out);
  } else if (S == 2) {
    flash_attn<2><<<16 * 8, 512, 0, stream>>>(qt, kt, vcm, Opart, l_g);
    proj_fused<2><<<dim3(64, 4), 256, 0, stream>>>(Opart, l_g, proj_w, proj_b,
                                                   x, out);
  } else {
    flash_attn<1><<<16 * 4, 512, 0, stream>>>(qt, kt, vcm, Opart, l_g);
    proj_fused<1><<<dim3(64, 4), 256, 0, stream>>>(Opart, l_g, proj_w, proj_b,
                                                   x, out);
  }
}